// Round 9
// baseline (639.040 us; speedup 1.0000x reference)
//
#include <hip/hip_runtime.h>
#include <math.h>

// ---------------- problem constants ----------------
#define NPIX 128
#define MASKM 2548
#define NPAD 2560          // padded q count (20*128)
#define MG   6912          // GEMM M = 9 taps * 768
#define KD   768
#define FUSED_GRID 512

typedef __attribute__((ext_vector_type(8))) short bf16x8;
typedef __attribute__((ext_vector_type(4))) float f32x4;
typedef __attribute__((ext_vector_type(16))) float f32x16;
typedef __attribute__((ext_vector_type(8))) unsigned short ushort8;

// ---------------- workspace layout ----------------
static constexpr size_t OFF_QI   = 0;
static constexpr size_t OFF_QJ   = OFF_QI + NPAD * 4;
static constexpr size_t OFF_QIDX = OFF_QJ + NPAD * 4;
static constexpr size_t OFF_APIX = OFF_QIDX + 16384 * 4;
static constexpr size_t OFF_BAR  = OFF_APIX + 16384 * 4;   // 2 ints (grid barrier)
static constexpr size_t OFF_PART = OFF_BAR + 128 * 4;
static constexpr size_t OFF_SC   = OFF_PART + 512 * 8 * 8;
static constexpr size_t OFF_HM   = OFF_SC + NPAD * 4;
static constexpr size_t OFF_AH   = OFF_HM + (size_t)MASKM * KD * 4;
static constexpr size_t OFF_AL   = OFF_AH + (size_t)MG * KD * 2;
static constexpr size_t OFF_BH   = OFF_AL + (size_t)MG * KD * 2;
static constexpr size_t OFF_BL   = OFF_BH + (size_t)NPAD * KD * 2;
static constexpr size_t OFF_YT   = OFF_BL + (size_t)NPAD * KD * 2;

// ---------------- bf16 hi/lo split helpers ----------------
__device__ __forceinline__ unsigned short f2bf(float f) {
    unsigned u = __float_as_uint(f);
    u = u + 0x7FFFu + ((u >> 16) & 1u);       // RNE
    return (unsigned short)(u >> 16);
}
__device__ __forceinline__ float bf2f(unsigned short h) {
    return __uint_as_float(((unsigned)h) << 16);
}

// ---------------- mask structure (closed form) ----------------
__device__ __forceinline__ bool mask_allowed(int i, int d) {
    if (d == 0) return true;
    if (d <= 15) return true;
    if (d <= 31) return (d >= 17) && ((d & 1) == 1) && ((i & 1) == 0);
    if (d <= 63) return (d >= 35) && ((d & 3) == 3) && ((i & 3) == 0);
    return (d >= 71) && ((d & 7) == 7) && ((i & 7) == 0);
}
__device__ __forceinline__ bool masked_ij(int i, int j) {
    return (j >= i) && (j < NPIX) && (i >= 0) && mask_allowed(i, j - i);
}

// closed-form inverse: rank r within row i -> offset d. Segments:
//  c1 = min(16, 128-i)                       d = 0..15           (j<128)
//  c2 = i even:  odd d in [17, min(31,127-i)]
//  c3 = i%4==0:  d%4==3 in [35, min(63,127-i)]
//  c4 = i%8==0:  d%8==7 in [71, 127-i]
__device__ __forceinline__ int rank_to_d(int i, int r) {
    int rem = NPIX - i;
    int c1 = rem < 16 ? rem : 16;
    if (r < c1) return r;
    r -= c1;
    int h2 = (rem - 1) < 31 ? (rem - 1) : 31;
    int c2 = (((i & 1) == 0) && h2 >= 17) ? ((h2 - 17) >> 1) + 1 : 0;
    if (r < c2) return 17 + 2 * r;
    r -= c2;
    int h3 = (rem - 1) < 63 ? (rem - 1) : 63;
    int c3 = (((i & 3) == 0) && h3 >= 35) ? ((h3 - 35) >> 2) + 1 : 0;
    if (r < c3) return 35 + 4 * r;
    r -= c3;
    return 71 + 8 * r;
}

// ================= k_prep: fill(64) | buildB(48) | prepA(144) = 256 blocks ====
// fill:    pixel maps qi/qj/qidx/apix + zero part/bar (block 0)
// buildB:  16 channels/block: sparse max tables in LDS, write Bh/Bl DIRECTLY
//          (absorbs old k_buildX + k_trans; X buffer eliminated)
// prepA:   w1 reorder + bf16 hi/lo split (unchanged logic)
#define PREP_LDS 66816     // tab 16*8*128*4 = 65536 | cnt 512 | startv 516
#define PASTR 148

__global__ __launch_bounds__(256) void k_prep(const float* __restrict__ fea,
                                              const float* __restrict__ w1,
                                              int* __restrict__ qi, int* __restrict__ qj,
                                              int* __restrict__ qidx, int* __restrict__ apix,
                                              double* __restrict__ part, int* __restrict__ bar,
                                              unsigned short* __restrict__ Ah,
                                              unsigned short* __restrict__ Al,
                                              unsigned short* __restrict__ Bh,
                                              unsigned short* __restrict__ Bl) {
    extern __shared__ char smp[];
    int tid = threadIdx.x;
    int bid = blockIdx.x;

    if (bid < 64) {
        // ---------------- FILL ----------------
        int* cnt = (int*)smp;
        int* startv = cnt + NPIX;
        if (tid < NPIX) {
            int c = 0;
            for (int d = 0; tid + d < NPIX; ++d) if (mask_allowed(tid, d)) ++c;
            cnt[tid] = c;
        }
        __syncthreads();
        if (tid == 0) {
            int s = 0;
            for (int r = 0; r < NPIX; ++r) { startv[r] = s; s += cnt[r]; }
        }
        __syncthreads();
        int p = bid * 256 + tid;
        int i = p >> 7, j = p & 127;
        int q = -1;
        if (masked_ij(i, j)) {
            int d = j - i, r = 0;
            for (int dd = 0; dd < d; ++dd) r += mask_allowed(i, dd) ? 1 : 0;
            q = startv[i] + r;
            qi[q] = i; qj[q] = j;
        }
        qidx[p] = q;
        int act = 0;
        #pragma unroll
        for (int dy = -1; dy <= 1; ++dy)
            #pragma unroll
            for (int dx = -1; dx <= 1; ++dx)
                if (masked_ij(i + dy, j + dx)) act = 1;
        apix[p] = act;
        if (bid == 0) {
            if (tid < 8) part[tid] = 0.0;
            if (tid == 8) bar[0] = 0;
            if (tid == 9) bar[1] = 0;
        }
    } else if (bid < 112) {
        // ---------------- BUILD B (16 channels) ----------------
        float* tab = (float*)smp;                       // [c 16][lvl 8][x 128]
        int* cnt = (int*)(smp + 65536);
        int* startv = (int*)(smp + 66048);              // 129 ints
        int cb = bid - 64, c0 = cb * 16;
        if (tid < NPIX) {
            int c = 0;
            for (int d = 0; tid + d < NPIX; ++d) if (mask_allowed(tid, d)) ++c;
            cnt[tid] = c;
        }
        __syncthreads();
        if (tid == 0) {
            int s = 0;
            for (int r = 0; r < NPIX; ++r) { startv[r] = s; s += cnt[r]; }
            startv[NPIX] = s;
        }
        for (int idx = tid; idx < 16 * NPIX; idx += 256) {
            int c = idx >> 7, x = idx & 127;
            tab[(c * 8) * 128 + x] = fea[(size_t)(c0 + c) * NPIX + x];
        }
        __syncthreads();
        for (int lvl = 1; lvl < 8; ++lvl) {
            int half = 1 << (lvl - 1), full = 1 << lvl;
            for (int idx = tid; idx < 16 * NPIX; idx += 256) {
                int c = idx >> 7, x = idx & 127;
                if (x + full <= NPIX)
                    tab[(c * 8 + lvl) * 128 + x] =
                        fmaxf(tab[(c * 8 + lvl - 1) * 128 + x],
                              tab[(c * 8 + lvl - 1) * 128 + x + half]);
            }
            __syncthreads();
        }
        for (int q = tid; q < NPAD; q += 256) {
            ushort8 vh0 = {}, vh1 = {}, vl0 = {}, vl1 = {};
            if (q < MASKM) {
                int i = 0;
                #pragma unroll
                for (int s = 64; s >= 1; s >>= 1) {
                    int cand = i + s;
                    if (cand <= 127 && startv[cand] <= q) i = cand;
                }
                int d = rank_to_d(i, q - startv[i]);
                int j = i + d;
                int len = d + 1;
                int lvl = 31 - __clz(len);
                int x2 = j + 1 - (1 << lvl);
                #pragma unroll
                for (int c = 0; c < 8; ++c) {
                    float v = fmaxf(tab[(c * 8 + lvl) * 128 + i], tab[(c * 8 + lvl) * 128 + x2]);
                    unsigned short hh = f2bf(v);
                    vh0[c] = hh; vl0[c] = f2bf(v - bf2f(hh));
                }
                #pragma unroll
                for (int c = 0; c < 8; ++c) {
                    float v = fmaxf(tab[((c + 8) * 8 + lvl) * 128 + i], tab[((c + 8) * 8 + lvl) * 128 + x2]);
                    unsigned short hh = f2bf(v);
                    vh1[c] = hh; vl1[c] = f2bf(v - bf2f(hh));
                }
            }
            *(ushort8*)(Bh + (size_t)q * KD + c0)     = vh0;
            *(ushort8*)(Bh + (size_t)q * KD + c0 + 8) = vh1;
            *(ushort8*)(Bl + (size_t)q * KD + c0)     = vl0;
            *(ushort8*)(Bl + (size_t)q * KD + c0 + 8) = vl1;
        }
    } else {
        // ---------------- PREP A ----------------
        float* tile = (float*)smp;                      // [co 64][ci16*9tap]
        int pb = bid - 112;
        int co0 = (pb % 12) * 64, ci0 = (pb / 12) * 64;
        for (int s = 0; s < 4; ++s) {
            int cib = ci0 + s * 16;
            __syncthreads();
            for (int idx = tid; idx < 2304; idx += 256) {
                int row = idx / 36, c4 = idx % 36;
                float4 v = *(const float4*)(w1 + (size_t)(co0 + row) * MG + cib * 9 + c4 * 4);
                *(float4*)&tile[row * PASTR + c4 * 4] = v;
            }
            __syncthreads();
            for (int idx = tid; idx < 1152; idx += 256) {
                int tap = idx / 128;
                int rem = idx - tap * 128;
                int co = rem >> 1, half = rem & 1;
                ushort8 vh, vl;
                #pragma unroll
                for (int c = 0; c < 8; ++c) {
                    float v = tile[co * PASTR + (half * 8 + c) * 9 + tap];
                    unsigned short hi = f2bf(v);
                    vh[c] = hi;
                    vl[c] = f2bf(v - bf2f(hi));
                }
                size_t ob = (size_t)(tap * 768 + co0 + co) * KD + cib + half * 8;
                *(ushort8*)(Ah + ob) = vh;
                *(ushort8*)(Al + ob) = vl;
            }
        }
    }
}

// ---------------- bf16x3 MFMA GEMM (exact R7 structure: best measured 96us) ----
#define BUFSZ   73728      // Ah(16K) | Al(16K) | Bh(20K) | Bl(20K)
#define SB_BH   32768

__global__ __launch_bounds__(512, 1) void k_gemm(const unsigned short* __restrict__ Ah,
                                                 const unsigned short* __restrict__ Al,
                                                 const unsigned short* __restrict__ Bh,
                                                 const unsigned short* __restrict__ Bl,
                                                 float* __restrict__ Yt) {
    extern __shared__ char sm[];               // 2 * BUFSZ = 144 KB dynamic LDS
    int tid = threadIdx.x;
    int wave = tid >> 6, lane = tid & 63;

    int bid = (int)blockIdx.x;
    int xcd = bid & 7, loc = bid >> 3;         // 8 XCDs x 27 M-tiles
    int m0 = loc * 256, n0 = xcd * 320;

    int wm = (wave & 3) << 6, wn = (wave >> 2) * 160;
    int r32 = lane & 31, hi2 = lane >> 5;
    int rb  = (r32 >> 4) * 1024 + hi2 * 256 + (r32 & 15) * 16;
    int awb = (wm >> 4) * 1024 + rb;
    int bwb = (wn >> 4) * 1024 + rb;

    int lrow = lane & 15, lchk = lane >> 4;
    const unsigned short* sp[9];
    int so[9];
    #pragma unroll
    for (int s = 0; s < 9; ++s) {
        int gid = wave * 9 + s;
        const unsigned short* base;
        int row0, ldso;
        if (gid < 16)      { base = Ah; row0 = m0 + gid * 16;        ldso = gid * 1024; }
        else if (gid < 32) { base = Al; row0 = m0 + (gid - 16) * 16; ldso = 16384 + (gid - 16) * 1024; }
        else if (gid < 52) { base = Bh; row0 = n0 + (gid - 32) * 16; ldso = SB_BH + (gid - 32) * 1024; }
        else               { base = Bl; row0 = n0 + (gid - 52) * 16; ldso = SB_BH + 20480 + (gid - 52) * 1024; }
        sp[s] = base + (size_t)(row0 + lrow) * KD + lchk * 8;
        so[s] = ldso;
    }

    f32x16 acc[2][5] = {};
    char* CB = sm;
    char* NB = sm + BUFSZ;

    #define STAGE(DST, s, koff) __builtin_amdgcn_global_load_lds( \
        (const __attribute__((address_space(1))) unsigned int*)(sp[s] + (koff)), \
        (__attribute__((address_space(3))) unsigned int*)((DST) + so[s]), 16, 0, 0)
    #define ARD(hl, mf, ks) (*(const bf16x8*)(CB + (hl) * 16384 + awb + (mf) * 2048 + (ks) * 512))
    #define BRD(hl, nf, ks) (*(const bf16x8*)(CB + SB_BH + (hl) * 20480 + bwb + (nf) * 2048 + (ks) * 512))
    #define TRIP(mf, nf, xh, xl, yh, yl) \
        acc[mf][nf] = __builtin_amdgcn_mfma_f32_32x32x16_bf16(xh, yh, acc[mf][nf], 0, 0, 0); \
        acc[mf][nf] = __builtin_amdgcn_mfma_f32_32x32x16_bf16(xh, yl, acc[mf][nf], 0, 0, 0); \
        acc[mf][nf] = __builtin_amdgcn_mfma_f32_32x32x16_bf16(xl, yh, acc[mf][nf], 0, 0, 0);

    #pragma unroll
    for (int s = 0; s < 9; ++s) STAGE(CB, s, 0);
    __syncthreads();

    for (int t = 0; t < 24; ++t) {
        int kn = (t + 1) * 32;
        if (t < 23) {
            #pragma unroll
            for (int s = 0; s < 9; ++s) STAGE(NB, s, kn);
        }
        #pragma unroll
        for (int ks = 0; ks < 2; ++ks) {
            bf16x8 a0h = ARD(0, 0, ks), a0l = ARD(1, 0, ks);
            bf16x8 a1h = ARD(0, 1, ks), a1l = ARD(1, 1, ks);
            bf16x8 bxh = BRD(0, 0, ks), bxl = BRD(1, 0, ks);
            bf16x8 byh = BRD(0, 1, ks), byl = BRD(1, 1, ks);
            __builtin_amdgcn_s_setprio(1);
            TRIP(0, 0, a0h, a0l, bxh, bxl)
            TRIP(1, 0, a1h, a1l, bxh, bxl)
            __builtin_amdgcn_s_setprio(0);
            bxh = BRD(0, 2, ks); bxl = BRD(1, 2, ks);
            __builtin_amdgcn_s_setprio(1);
            TRIP(0, 1, a0h, a0l, byh, byl)
            TRIP(1, 1, a1h, a1l, byh, byl)
            __builtin_amdgcn_s_setprio(0);
            byh = BRD(0, 3, ks); byl = BRD(1, 3, ks);
            __builtin_amdgcn_s_setprio(1);
            TRIP(0, 2, a0h, a0l, bxh, bxl)
            TRIP(1, 2, a1h, a1l, bxh, bxl)
            __builtin_amdgcn_s_setprio(0);
            bxh = BRD(0, 4, ks); bxl = BRD(1, 4, ks);
            __builtin_amdgcn_s_setprio(1);
            TRIP(0, 3, a0h, a0l, byh, byl)
            TRIP(1, 3, a1h, a1l, byh, byl)
            TRIP(0, 4, a0h, a0l, bxh, bxl)
            TRIP(1, 4, a1h, a1l, bxh, bxl)
            __builtin_amdgcn_s_setprio(0);
        }
        __syncthreads();
        char* tmp = CB; CB = NB; NB = tmp;
    }

    #pragma unroll
    for (int mf = 0; mf < 2; ++mf)
        #pragma unroll
        for (int nf = 0; nf < 5; ++nf) {
            int n = n0 + wn + nf * 32 + r32;
            size_t rowb = (size_t)n * MG + m0 + wm + mf * 32 + 4 * hi2;
            #pragma unroll
            for (int g = 0; g < 4; ++g) {
                f32x4 v = { acc[mf][nf][g * 4 + 0], acc[mf][nf][g * 4 + 1],
                            acc[mf][nf][g * 4 + 2], acc[mf][nf][g * 4 + 3] };
                *(f32x4*)(Yt + rowb + 8 * g) = v;
            }
        }
    #undef STAGE
    #undef ARD
    #undef BRD
    #undef TRIP
}

// ================= k_fused: gather -> [grid bar] -> score -> [grid bar] -> nms ==
// 512 blocks x 256 thr, launch_bounds(256,3) + 44KB LDS -> >=3 blocks/CU capacity
// (768 >= 512) so all blocks co-resident: atomic-counter grid barrier is safe.
// bar[] re-zeroed by k_prep each iteration (graph-replay safe).
#define FUSED_LDS 44544

__device__ __forceinline__ void grid_arrive_wait(int* ctr) {
    __threadfence();
    __syncthreads();
    if (threadIdx.x == 0) {
        __hip_atomic_fetch_add(ctr, 1, __ATOMIC_RELEASE, __HIP_MEMORY_SCOPE_AGENT);
        while (__hip_atomic_load(ctr, __ATOMIC_ACQUIRE, __HIP_MEMORY_SCOPE_AGENT) < FUSED_GRID)
            __builtin_amdgcn_s_sleep(1);
    }
    __syncthreads();
    __threadfence();
}

__global__ __launch_bounds__(256, 3) void k_fused(const float* __restrict__ Yt,
                                                  const int* __restrict__ qidx,
                                                  const int* __restrict__ apix,
                                                  const int* __restrict__ qi,
                                                  const int* __restrict__ qj,
                                                  const int* __restrict__ durp,
                                                  double* __restrict__ part,
                                                  int* __restrict__ bar,
                                                  float* __restrict__ hm,
                                                  float* __restrict__ scores,
                                                  const float* __restrict__ gamma,
                                                  const float* __restrict__ beta,
                                                  const float* __restrict__ w2,
                                                  const float* __restrict__ b2,
                                                  float* __restrict__ out) {
    extern __shared__ char smf[];
    int tid = threadIdx.x;
    int bid = (int)blockIdx.x;
    int wave = tid >> 6, lane = tid & 63;

    // ---------------- phase 1: gather (identical arithmetic to old k_gather) ----
    {
        double* red1 = (double*)smf;            // [256*4]
        double* red2 = red1 + 1024;             // [256*4]
        double a1[3] = {0, 0, 0}, a2[3] = {0, 0, 0};
        int gs[3];
        #pragma unroll
        for (int s = 0; s < 3; ++s) gs[s] = (64 * s + lane) / 48;

        for (int it = 0; it < 8; ++it) {
            int p = bid * 32 + wave * 8 + it;
            if (!apix[p]) continue;
            int y = p >> 7, x = p & 127;
            float4 hv[3] = {};
            #pragma unroll
            for (int tap = 0; tap < 9; ++tap) {
                int i = y + tap / 3 - 1, j = x + tap % 3 - 1;
                if ((unsigned)i < 128u && (unsigned)j < 128u) {
                    int q = qidx[i * NPIX + j];
                    if (q >= 0) {
                        const float* yr = Yt + (size_t)q * MG + tap * 768 + lane * 4;
                        #pragma unroll
                        for (int s = 0; s < 3; ++s) {
                            float4 v = *(const float4*)(yr + s * 256);
                            hv[s].x += v.x; hv[s].y += v.y; hv[s].z += v.z; hv[s].w += v.w;
                        }
                    }
                }
            }
            int qp = qidx[p];
            if (qp >= 0) {
                #pragma unroll
                for (int s = 0; s < 3; ++s)
                    *(float4*)(hm + (size_t)qp * KD + s * 256 + lane * 4) = hv[s];
            }
            #pragma unroll
            for (int s = 0; s < 3; ++s) {
                a1[s] += (double)hv[s].x + (double)hv[s].y + (double)hv[s].z + (double)hv[s].w;
                a2[s] += (double)hv[s].x * hv[s].x + (double)hv[s].y * hv[s].y +
                         (double)hv[s].z * hv[s].z + (double)hv[s].w * hv[s].w;
            }
        }
        #pragma unroll
        for (int g = 0; g < 4; ++g) { red1[tid * 4 + g] = 0.0; red2[tid * 4 + g] = 0.0; }
        #pragma unroll
        for (int s = 0; s < 3; ++s) { red1[tid * 4 + gs[s]] = a1[s]; red2[tid * 4 + gs[s]] = a2[s]; }
        __syncthreads();
        if (tid < 8) {
            int g = tid & 3;
            double s = 0.0;
            if (tid < 4) { for (int i = 0; i < 256; ++i) s += red1[i * 4 + g]; }
            else         { for (int i = 0; i < 256; ++i) s += red2[i * 4 + g]; }
            atomicAdd(&part[tid], s);
        }
    }

    grid_arrive_wait(&bar[0]);

    // ---------------- phase 2: score (identical per-q arithmetic) --------------
    {
        float mu[4], rs[4];
        const double cnt = 192.0 * 16384.0;
        #pragma unroll
        for (int g = 0; g < 4; ++g) {
            double m = *((volatile double*)&part[g]) / cnt;
            double v = *((volatile double*)&part[4 + g]) / cnt - m * m;
            mu[g] = (float)m;
            rs[g] = (float)(1.0 / sqrt(v + 1e-5));
        }
        #pragma unroll
        for (int rep = 0; rep < 2; ++rep) {
            int q = bid * 4 + wave + rep * 2048;
            if (q < MASKM) {
                const float* hp = hm + (size_t)q * KD;
                float s = 0.f;
                for (int c = lane; c < KD; c += 64) {
                    int g = c / 192;
                    float v = (hp[c] - mu[g]) * rs[g] * gamma[c] + beta[c];
                    s += fmaxf(v, 0.f) * w2[c];
                }
                for (int o = 32; o; o >>= 1) s += __shfl_down(s, o, 64);
                if (lane == 0) scores[q] = 1.f / (1.f + expf(-(s + b2[0])));
            }
        }
    }

    // ---------------- phase 3: barrier; block 0 runs NMS ------------------------
    __threadfence();
    __syncthreads();
    if (tid == 0)
        __hip_atomic_fetch_add(&bar[1], 1, __ATOMIC_RELEASE, __HIP_MEMORY_SCOPE_AGENT);
    if (bid != 0) return;
    if (tid == 0) {
        while (__hip_atomic_load(&bar[1], __ATOMIC_ACQUIRE, __HIP_MEMORY_SCOPE_AGENT) < FUSED_GRID)
            __builtin_amdgcn_s_sleep(1);
    }
    __syncthreads();
    __threadfence();

    {
        unsigned long long* key = (unsigned long long*)smf;          // 2548*8 = 20384
        float* ss = (float*)(smf + 20384);                           // 10192
        float* ee = (float*)(smf + 30576);                           // 10192
        unsigned char* st = (unsigned char*)(smf + 40768);           // 2560
        unsigned long long* wm0 = (unsigned long long*)(smf + 43328);// 4
        unsigned long long* wm1 = (unsigned long long*)(smf + 43360);// 4
        __shared__ int sh_keeper, keepq[5];
        __shared__ float sh_s0, sh_e0;

        float delta = (float)(*durp) / 128.f;
        for (int i = tid; i < MASKM; i += 256) {
            unsigned sb = __float_as_uint(scores[i]);
            key[i] = ((unsigned long long)sb << 32) | (unsigned)(4095 - i);
            ss[i] = qi[i] * delta;
            ee[i] = (qj[i] + 1) * delta;
            st[i] = 0;
        }
        __syncthreads();
        for (int round = 0; round < 5; ++round) {
            unsigned long long b0 = 0, b1 = 0;
            for (int i = tid; i < MASKM; i += 256) {
                unsigned char s = st[i];
                unsigned long long k = key[i];
                if (s == 0) { if (k > b0) b0 = k; }
                else if (s == 1) { if (k > b1) b1 = k; }
            }
            for (int o = 32; o; o >>= 1) {
                unsigned lo0 = __shfl_down((unsigned)b0, o, 64);
                unsigned hi0 = __shfl_down((unsigned)(b0 >> 32), o, 64);
                unsigned long long u0 = ((unsigned long long)hi0 << 32) | lo0;
                unsigned lo1 = __shfl_down((unsigned)b1, o, 64);
                unsigned hi1 = __shfl_down((unsigned)(b1 >> 32), o, 64);
                unsigned long long u1 = ((unsigned long long)hi1 << 32) | lo1;
                if (u0 > b0) b0 = u0;
                if (u1 > b1) b1 = u1;
            }
            if ((tid & 63) == 0) { wm0[tid >> 6] = b0; wm1[tid >> 6] = b1; }
            __syncthreads();
            if (tid == 0) {
                unsigned long long B0 = 0, B1 = 0;
                for (int w = 0; w < 4; ++w) {
                    if (wm0[w] > B0) B0 = wm0[w];
                    if (wm1[w] > B1) B1 = wm1[w];
                }
                int keeper = (B0 != 0);
                unsigned long long B = keeper ? B0 : B1;
                int q = 4095 - (int)(B & 0xFFFFFFFFull);
                st[q] = keeper ? 2 : 3;
                sh_keeper = keeper;
                sh_s0 = ss[q]; sh_e0 = ee[q];
                keepq[round] = q;
            }
            __syncthreads();
            if (sh_keeper) {
                float s0 = sh_s0, e0 = sh_e0;
                for (int i = tid; i < MASKM; i += 256) {
                    if (st[i] == 0) {
                        float inter = fminf(ee[i], e0) - fmaxf(ss[i], s0);
                        if (inter > 0.f) {
                            float uni = fmaxf(ee[i], e0) - fminf(ss[i], s0);
                            if (inter / uni > 0.5f) st[i] = 1;
                        }
                    }
                }
            }
            __syncthreads();
        }
        if (tid < 5) { out[tid * 2] = ss[keepq[tid]]; out[tid * 2 + 1] = ee[keepq[tid]]; }
    }
}

// ---------------- launch ----------------
extern "C" void kernel_launch(void* const* d_in, const int* in_sizes, int n_in,
                              void* d_out, int out_size, void* d_ws, size_t ws_size,
                              hipStream_t stream) {
    const float* fea   = (const float*)d_in[0];
    const int*   dur   = (const int*)d_in[1];
    const float* w1    = (const float*)d_in[2];
    const float* gamma = (const float*)d_in[3];
    const float* beta  = (const float*)d_in[4];
    const float* w2    = (const float*)d_in[5];
    const float* b2    = (const float*)d_in[6];
    float* out = (float*)d_out;

    char* ws = (char*)d_ws;
    int*    qi     = (int*)(ws + OFF_QI);
    int*    qj     = (int*)(ws + OFF_QJ);
    int*    qidx   = (int*)(ws + OFF_QIDX);
    int*    apix   = (int*)(ws + OFF_APIX);
    int*    bar    = (int*)(ws + OFF_BAR);
    double* part   = (double*)(ws + OFF_PART);
    float*  scores = (float*)(ws + OFF_SC);
    float*  hm     = (float*)(ws + OFF_HM);
    unsigned short* AhU = (unsigned short*)(ws + OFF_AH);
    unsigned short* AlU = (unsigned short*)(ws + OFF_AL);
    unsigned short* BhU = (unsigned short*)(ws + OFF_BH);
    unsigned short* BlU = (unsigned short*)(ws + OFF_BL);
    float*  Yt     = (float*)(ws + OFF_YT);

    static bool attr_set = false;
    if (!attr_set) {
        hipFuncSetAttribute((const void*)k_prep,
                            hipFuncAttributeMaxDynamicSharedMemorySize, PREP_LDS);
        hipFuncSetAttribute((const void*)k_gemm,
                            hipFuncAttributeMaxDynamicSharedMemorySize, 2 * BUFSZ);
        hipFuncSetAttribute((const void*)k_fused,
                            hipFuncAttributeMaxDynamicSharedMemorySize, FUSED_LDS);
        attr_set = true;
    }

    k_prep<<<256, 256, PREP_LDS, stream>>>(fea, w1, qi, qj, qidx, apix, part, bar,
                                           AhU, AlU, BhU, BlU);
    k_gemm<<<216, 512, 2 * BUFSZ, stream>>>(AhU, AlU, BhU, BlU, Yt);
    k_fused<<<FUSED_GRID, 256, FUSED_LDS, stream>>>(Yt, qidx, apix, qi, qj, dur, part, bar,
                                                    hm, scores, gamma, beta, w2, b2, out);
}

// Round 10
// 273.531 us; speedup vs baseline: 2.3363x; 2.3363x over previous
//
#include <hip/hip_runtime.h>
#include <math.h>

// ---------------- problem constants ----------------
#define NPIX 128
#define MASKM 2548
#define NPAD 2560          // padded q count (20*128)
#define MG   6912          // GEMM M = 9 taps * 768
#define KD   768

typedef __attribute__((ext_vector_type(8))) short bf16x8;
typedef __attribute__((ext_vector_type(4))) float f32x4;
typedef __attribute__((ext_vector_type(16))) float f32x16;
typedef __attribute__((ext_vector_type(8))) unsigned short ushort8;

// ---------------- workspace layout ----------------
static constexpr size_t OFF_QI   = 0;
static constexpr size_t OFF_QJ   = OFF_QI + NPAD * 4;
static constexpr size_t OFF_QIDX = OFF_QJ + NPAD * 4;
static constexpr size_t OFF_APIX = OFF_QIDX + 16384 * 4;
static constexpr size_t OFF_BAR  = OFF_APIX + 16384 * 4;   // 4 ints (sync counters)
static constexpr size_t OFF_PART = OFF_BAR + 128 * 4;
static constexpr size_t OFF_SC   = OFF_PART + 512 * 8 * 8;
static constexpr size_t OFF_HM   = OFF_SC + NPAD * 4;
static constexpr size_t OFF_AH   = OFF_HM + (size_t)MASKM * KD * 4;
static constexpr size_t OFF_AL   = OFF_AH + (size_t)MG * KD * 2;
static constexpr size_t OFF_BH   = OFF_AL + (size_t)MG * KD * 2;
static constexpr size_t OFF_BL   = OFF_BH + (size_t)NPAD * KD * 2;
static constexpr size_t OFF_YT   = OFF_BL + (size_t)NPAD * KD * 2;

// ---------------- bf16 hi/lo split helpers ----------------
__device__ __forceinline__ unsigned short f2bf(float f) {
    unsigned u = __float_as_uint(f);
    u = u + 0x7FFFu + ((u >> 16) & 1u);       // RNE
    return (unsigned short)(u >> 16);
}
__device__ __forceinline__ float bf2f(unsigned short h) {
    return __uint_as_float(((unsigned)h) << 16);
}

// ---------------- mask structure (closed form) ----------------
__device__ __forceinline__ bool mask_allowed(int i, int d) {
    if (d == 0) return true;
    if (d <= 15) return true;
    if (d <= 31) return (d >= 17) && ((d & 1) == 1) && ((i & 1) == 0);
    if (d <= 63) return (d >= 35) && ((d & 3) == 3) && ((i & 3) == 0);
    return (d >= 71) && ((d & 7) == 7) && ((i & 7) == 0);
}
__device__ __forceinline__ bool masked_ij(int i, int j) {
    return (j >= i) && (j < NPIX) && (i >= 0) && mask_allowed(i, j - i);
}

// closed-form inverse: rank r within row i -> offset d.
__device__ __forceinline__ int rank_to_d(int i, int r) {
    int rem = NPIX - i;
    int c1 = rem < 16 ? rem : 16;
    if (r < c1) return r;
    r -= c1;
    int h2 = (rem - 1) < 31 ? (rem - 1) : 31;
    int c2 = (((i & 1) == 0) && h2 >= 17) ? ((h2 - 17) >> 1) + 1 : 0;
    if (r < c2) return 17 + 2 * r;
    r -= c2;
    int h3 = (rem - 1) < 63 ? (rem - 1) : 63;
    int c3 = (((i & 3) == 0) && h3 >= 35) ? ((h3 - 35) >> 2) + 1 : 0;
    if (r < c3) return 35 + 4 * r;
    r -= c3;
    return 71 + 8 * r;
}

// ================= k_prep: fill(64) | buildB(48) | prepA(144) = 256 blocks ====
// (verified R9) fill: pixel maps + zero part/bar. buildB: 16ch sparse-max tables
// in LDS, writes Bh/Bl directly (k_buildX+k_trans+X eliminated). prepA: w1 split.
#define PREP_LDS 66816
#define PASTR 148

__global__ __launch_bounds__(256) void k_prep(const float* __restrict__ fea,
                                              const float* __restrict__ w1,
                                              int* __restrict__ qi, int* __restrict__ qj,
                                              int* __restrict__ qidx, int* __restrict__ apix,
                                              double* __restrict__ part, int* __restrict__ bar,
                                              unsigned short* __restrict__ Ah,
                                              unsigned short* __restrict__ Al,
                                              unsigned short* __restrict__ Bh,
                                              unsigned short* __restrict__ Bl) {
    extern __shared__ char smp[];
    int tid = threadIdx.x;
    int bid = blockIdx.x;

    if (bid < 64) {
        // ---------------- FILL ----------------
        int* cnt = (int*)smp;
        int* startv = cnt + NPIX;
        if (tid < NPIX) {
            int c = 0;
            for (int d = 0; tid + d < NPIX; ++d) if (mask_allowed(tid, d)) ++c;
            cnt[tid] = c;
        }
        __syncthreads();
        if (tid == 0) {
            int s = 0;
            for (int r = 0; r < NPIX; ++r) { startv[r] = s; s += cnt[r]; }
        }
        __syncthreads();
        int p = bid * 256 + tid;
        int i = p >> 7, j = p & 127;
        int q = -1;
        if (masked_ij(i, j)) {
            int d = j - i, r = 0;
            for (int dd = 0; dd < d; ++dd) r += mask_allowed(i, dd) ? 1 : 0;
            q = startv[i] + r;
            qi[q] = i; qj[q] = j;
        }
        qidx[p] = q;
        int act = 0;
        #pragma unroll
        for (int dy = -1; dy <= 1; ++dy)
            #pragma unroll
            for (int dx = -1; dx <= 1; ++dx)
                if (masked_ij(i + dy, j + dx)) act = 1;
        apix[p] = act;
        if (bid == 0) {
            if (tid < 8) part[tid] = 0.0;
            if (tid >= 8 && tid < 12) bar[tid - 8] = 0;
        }
    } else if (bid < 112) {
        // ---------------- BUILD B (16 channels) ----------------
        float* tab = (float*)smp;                       // [c 16][lvl 8][x 128]
        int* cnt = (int*)(smp + 65536);
        int* startv = (int*)(smp + 66048);              // 129 ints
        int cb = bid - 64, c0 = cb * 16;
        if (tid < NPIX) {
            int c = 0;
            for (int d = 0; tid + d < NPIX; ++d) if (mask_allowed(tid, d)) ++c;
            cnt[tid] = c;
        }
        __syncthreads();
        if (tid == 0) {
            int s = 0;
            for (int r = 0; r < NPIX; ++r) { startv[r] = s; s += cnt[r]; }
            startv[NPIX] = s;
        }
        for (int idx = tid; idx < 16 * NPIX; idx += 256) {
            int c = idx >> 7, x = idx & 127;
            tab[(c * 8) * 128 + x] = fea[(size_t)(c0 + c) * NPIX + x];
        }
        __syncthreads();
        for (int lvl = 1; lvl < 8; ++lvl) {
            int half = 1 << (lvl - 1), full = 1 << lvl;
            for (int idx = tid; idx < 16 * NPIX; idx += 256) {
                int c = idx >> 7, x = idx & 127;
                if (x + full <= NPIX)
                    tab[(c * 8 + lvl) * 128 + x] =
                        fmaxf(tab[(c * 8 + lvl - 1) * 128 + x],
                              tab[(c * 8 + lvl - 1) * 128 + x + half]);
            }
            __syncthreads();
        }
        for (int q = tid; q < NPAD; q += 256) {
            ushort8 vh0 = {}, vh1 = {}, vl0 = {}, vl1 = {};
            if (q < MASKM) {
                int i = 0;
                #pragma unroll
                for (int s = 64; s >= 1; s >>= 1) {
                    int cand = i + s;
                    if (cand <= 127 && startv[cand] <= q) i = cand;
                }
                int d = rank_to_d(i, q - startv[i]);
                int j = i + d;
                int len = d + 1;
                int lvl = 31 - __clz(len);
                int x2 = j + 1 - (1 << lvl);
                #pragma unroll
                for (int c = 0; c < 8; ++c) {
                    float v = fmaxf(tab[(c * 8 + lvl) * 128 + i], tab[(c * 8 + lvl) * 128 + x2]);
                    unsigned short hh = f2bf(v);
                    vh0[c] = hh; vl0[c] = f2bf(v - bf2f(hh));
                }
                #pragma unroll
                for (int c = 0; c < 8; ++c) {
                    float v = fmaxf(tab[((c + 8) * 8 + lvl) * 128 + i], tab[((c + 8) * 8 + lvl) * 128 + x2]);
                    unsigned short hh = f2bf(v);
                    vh1[c] = hh; vl1[c] = f2bf(v - bf2f(hh));
                }
            }
            *(ushort8*)(Bh + (size_t)q * KD + c0)     = vh0;
            *(ushort8*)(Bh + (size_t)q * KD + c0 + 8) = vh1;
            *(ushort8*)(Bl + (size_t)q * KD + c0)     = vl0;
            *(ushort8*)(Bl + (size_t)q * KD + c0 + 8) = vl1;
        }
    } else {
        // ---------------- PREP A ----------------
        float* tile = (float*)smp;
        int pb = bid - 112;
        int co0 = (pb % 12) * 64, ci0 = (pb / 12) * 64;
        for (int s = 0; s < 4; ++s) {
            int cib = ci0 + s * 16;
            __syncthreads();
            for (int idx = tid; idx < 2304; idx += 256) {
                int row = idx / 36, c4 = idx % 36;
                float4 v = *(const float4*)(w1 + (size_t)(co0 + row) * MG + cib * 9 + c4 * 4);
                *(float4*)&tile[row * PASTR + c4 * 4] = v;
            }
            __syncthreads();
            for (int idx = tid; idx < 1152; idx += 256) {
                int tap = idx / 128;
                int rem = idx - tap * 128;
                int co = rem >> 1, half = rem & 1;
                ushort8 vh, vl;
                #pragma unroll
                for (int c = 0; c < 8; ++c) {
                    float v = tile[co * PASTR + (half * 8 + c) * 9 + tap];
                    unsigned short hi = f2bf(v);
                    vh[c] = hi;
                    vl[c] = f2bf(v - bf2f(hi));
                }
                size_t ob = (size_t)(tap * 768 + co0 + co) * KD + cib + half * 8;
                *(ushort8*)(Ah + ob) = vh;
                *(ushort8*)(Al + ob) = vl;
            }
        }
    }
}

// ---------------- bf16x3 MFMA GEMM (exact R7 structure: best measured 96us) ----
#define BUFSZ   73728      // Ah(16K) | Al(16K) | Bh(20K) | Bl(20K)
#define SB_BH   32768

__global__ __launch_bounds__(512, 1) void k_gemm(const unsigned short* __restrict__ Ah,
                                                 const unsigned short* __restrict__ Al,
                                                 const unsigned short* __restrict__ Bh,
                                                 const unsigned short* __restrict__ Bl,
                                                 float* __restrict__ Yt) {
    extern __shared__ char sm[];               // 2 * BUFSZ = 144 KB dynamic LDS
    int tid = threadIdx.x;
    int wave = tid >> 6, lane = tid & 63;

    int bid = (int)blockIdx.x;
    int xcd = bid & 7, loc = bid >> 3;         // 8 XCDs x 27 M-tiles
    int m0 = loc * 256, n0 = xcd * 320;

    int wm = (wave & 3) << 6, wn = (wave >> 2) * 160;
    int r32 = lane & 31, hi2 = lane >> 5;
    int rb  = (r32 >> 4) * 1024 + hi2 * 256 + (r32 & 15) * 16;
    int awb = (wm >> 4) * 1024 + rb;
    int bwb = (wn >> 4) * 1024 + rb;

    int lrow = lane & 15, lchk = lane >> 4;
    const unsigned short* sp[9];
    int so[9];
    #pragma unroll
    for (int s = 0; s < 9; ++s) {
        int gid = wave * 9 + s;
        const unsigned short* base;
        int row0, ldso;
        if (gid < 16)      { base = Ah; row0 = m0 + gid * 16;        ldso = gid * 1024; }
        else if (gid < 32) { base = Al; row0 = m0 + (gid - 16) * 16; ldso = 16384 + (gid - 16) * 1024; }
        else if (gid < 52) { base = Bh; row0 = n0 + (gid - 32) * 16; ldso = SB_BH + (gid - 32) * 1024; }
        else               { base = Bl; row0 = n0 + (gid - 52) * 16; ldso = SB_BH + 20480 + (gid - 52) * 1024; }
        sp[s] = base + (size_t)(row0 + lrow) * KD + lchk * 8;
        so[s] = ldso;
    }

    f32x16 acc[2][5] = {};
    char* CB = sm;
    char* NB = sm + BUFSZ;

    #define STAGE(DST, s, koff) __builtin_amdgcn_global_load_lds( \
        (const __attribute__((address_space(1))) unsigned int*)(sp[s] + (koff)), \
        (__attribute__((address_space(3))) unsigned int*)((DST) + so[s]), 16, 0, 0)
    #define ARD(hl, mf, ks) (*(const bf16x8*)(CB + (hl) * 16384 + awb + (mf) * 2048 + (ks) * 512))
    #define BRD(hl, nf, ks) (*(const bf16x8*)(CB + SB_BH + (hl) * 20480 + bwb + (nf) * 2048 + (ks) * 512))
    #define TRIP(mf, nf, xh, xl, yh, yl) \
        acc[mf][nf] = __builtin_amdgcn_mfma_f32_32x32x16_bf16(xh, yh, acc[mf][nf], 0, 0, 0); \
        acc[mf][nf] = __builtin_amdgcn_mfma_f32_32x32x16_bf16(xh, yl, acc[mf][nf], 0, 0, 0); \
        acc[mf][nf] = __builtin_amdgcn_mfma_f32_32x32x16_bf16(xl, yh, acc[mf][nf], 0, 0, 0);

    #pragma unroll
    for (int s = 0; s < 9; ++s) STAGE(CB, s, 0);
    __syncthreads();

    for (int t = 0; t < 24; ++t) {
        int kn = (t + 1) * 32;
        if (t < 23) {
            #pragma unroll
            for (int s = 0; s < 9; ++s) STAGE(NB, s, kn);
        }
        #pragma unroll
        for (int ks = 0; ks < 2; ++ks) {
            bf16x8 a0h = ARD(0, 0, ks), a0l = ARD(1, 0, ks);
            bf16x8 a1h = ARD(0, 1, ks), a1l = ARD(1, 1, ks);
            bf16x8 bxh = BRD(0, 0, ks), bxl = BRD(1, 0, ks);
            bf16x8 byh = BRD(0, 1, ks), byl = BRD(1, 1, ks);
            __builtin_amdgcn_s_setprio(1);
            TRIP(0, 0, a0h, a0l, bxh, bxl)
            TRIP(1, 0, a1h, a1l, bxh, bxl)
            __builtin_amdgcn_s_setprio(0);
            bxh = BRD(0, 2, ks); bxl = BRD(1, 2, ks);
            __builtin_amdgcn_s_setprio(1);
            TRIP(0, 1, a0h, a0l, byh, byl)
            TRIP(1, 1, a1h, a1l, byh, byl)
            __builtin_amdgcn_s_setprio(0);
            byh = BRD(0, 3, ks); byl = BRD(1, 3, ks);
            __builtin_amdgcn_s_setprio(1);
            TRIP(0, 2, a0h, a0l, bxh, bxl)
            TRIP(1, 2, a1h, a1l, bxh, bxl)
            __builtin_amdgcn_s_setprio(0);
            bxh = BRD(0, 4, ks); bxl = BRD(1, 4, ks);
            __builtin_amdgcn_s_setprio(1);
            TRIP(0, 3, a0h, a0l, byh, byl)
            TRIP(1, 3, a1h, a1l, byh, byl)
            TRIP(0, 4, a0h, a0l, bxh, bxl)
            TRIP(1, 4, a1h, a1l, bxh, bxl)
            __builtin_amdgcn_s_setprio(0);
        }
        __syncthreads();
        char* tmp = CB; CB = NB; NB = tmp;
    }

    #pragma unroll
    for (int mf = 0; mf < 2; ++mf)
        #pragma unroll
        for (int nf = 0; nf < 5; ++nf) {
            int n = n0 + wn + nf * 32 + r32;
            size_t rowb = (size_t)n * MG + m0 + wm + mf * 32 + 4 * hi2;
            #pragma unroll
            for (int g = 0; g < 4; ++g) {
                f32x4 v = { acc[mf][nf][g * 4 + 0], acc[mf][nf][g * 4 + 1],
                            acc[mf][nf][g * 4 + 2], acc[mf][nf][g * 4 + 3] };
                *(f32x4*)(Yt + rowb + 8 * g) = v;
            }
        }
    #undef STAGE
    #undef ARD
    #undef BRD
    #undef TRIP
}

// ---------------- gather taps -> hm + GN partial sums (standalone, R7-proven) ---
__global__ __launch_bounds__(256) void k_gather(const float* __restrict__ Yt,
                                                const int* __restrict__ qidx,
                                                const int* __restrict__ apix,
                                                float* __restrict__ hm,
                                                double* __restrict__ part) {
    __shared__ double red1[256 * 4], red2[256 * 4];
    int tid = threadIdx.x;
    int wave = tid >> 6, lane = tid & 63;
    double a1[3] = {0, 0, 0}, a2[3] = {0, 0, 0};
    int gs[3];
    #pragma unroll
    for (int s = 0; s < 3; ++s) gs[s] = (64 * s + lane) / 48;

    for (int it = 0; it < 8; ++it) {
        int p = blockIdx.x * 32 + wave * 8 + it;
        if (!apix[p]) continue;
        int y = p >> 7, x = p & 127;
        float4 hv[3] = {};
        #pragma unroll
        for (int tap = 0; tap < 9; ++tap) {
            int i = y + tap / 3 - 1, j = x + tap % 3 - 1;
            if ((unsigned)i < 128u && (unsigned)j < 128u) {
                int q = qidx[i * NPIX + j];
                if (q >= 0) {
                    const float* yr = Yt + (size_t)q * MG + tap * 768 + lane * 4;
                    #pragma unroll
                    for (int s = 0; s < 3; ++s) {
                        float4 v = *(const float4*)(yr + s * 256);
                        hv[s].x += v.x; hv[s].y += v.y; hv[s].z += v.z; hv[s].w += v.w;
                    }
                }
            }
        }
        int qp = qidx[p];
        if (qp >= 0) {
            #pragma unroll
            for (int s = 0; s < 3; ++s)
                *(float4*)(hm + (size_t)qp * KD + s * 256 + lane * 4) = hv[s];
        }
        #pragma unroll
        for (int s = 0; s < 3; ++s) {
            a1[s] += (double)hv[s].x + (double)hv[s].y + (double)hv[s].z + (double)hv[s].w;
            a2[s] += (double)hv[s].x * hv[s].x + (double)hv[s].y * hv[s].y +
                     (double)hv[s].z * hv[s].z + (double)hv[s].w * hv[s].w;
        }
    }
    #pragma unroll
    for (int g = 0; g < 4; ++g) { red1[tid * 4 + g] = 0.0; red2[tid * 4 + g] = 0.0; }
    #pragma unroll
    for (int s = 0; s < 3; ++s) { red1[tid * 4 + gs[s]] = a1[s]; red2[tid * 4 + gs[s]] = a2[s]; }
    __syncthreads();
    if (tid < 8) {
        int g = tid & 3;
        double s = 0.0;
        if (tid < 4) { for (int i = 0; i < 256; ++i) s += red1[i * 4 + g]; }
        else         { for (int i = 0; i < 256; ++i) s += red2[i * 4 + g]; }
        atomicAdd(&part[tid], s);
    }
}

// ================= k_scorenms: score (637 blocks) + single-consumer NMS ========
// Each block RELEASE-adds the done-counter once after writing its 4 scores.
// ONLY block 0 waits: RELAXED polls (no per-poll cache maintenance — R9's 460us
// came from per-poll agent-ACQUIRE = full per-XCD L2 invalidate each iteration)
// + one ACQUIRE load after the count hits 637. Block 0 is first-dispatched ->
// resident -> no deadlock at any occupancy. NMS = R9's verified 256-thread form.
#define SNMS_LDS 44544

__global__ __launch_bounds__(256) void k_scorenms(const float* __restrict__ hm,
                                                  const double* __restrict__ part,
                                                  const float* __restrict__ gamma,
                                                  const float* __restrict__ beta,
                                                  const float* __restrict__ w2,
                                                  const float* __restrict__ b2,
                                                  float* __restrict__ scores,
                                                  const int* __restrict__ qi,
                                                  const int* __restrict__ qj,
                                                  const int* __restrict__ durp,
                                                  int* __restrict__ bar,
                                                  float* __restrict__ out) {
    extern __shared__ char smf[];
    int tid = threadIdx.x;
    int bid = (int)blockIdx.x;
    int lane = tid & 63;

    // ---- score phase (identical arithmetic to R7 k_score; 637*4 = 2548 exact) ----
    {
        float mu[4], rs[4];
        const double cnt = 192.0 * 16384.0;
        #pragma unroll
        for (int g = 0; g < 4; ++g) {
            double m = part[g] / cnt;
            double v = part[4 + g] / cnt - m * m;
            mu[g] = (float)m;
            rs[g] = (float)(1.0 / sqrt(v + 1e-5));
        }
        int q = bid * 4 + (tid >> 6);
        const float* hp = hm + (size_t)q * KD;
        float s = 0.f;
        for (int c = lane; c < KD; c += 64) {
            int g = c / 192;
            float v = (hp[c] - mu[g]) * rs[g] * gamma[c] + beta[c];
            s += fmaxf(v, 0.f) * w2[c];
        }
        for (int o = 32; o; o >>= 1) s += __shfl_down(s, o, 64);
        if (lane == 0) scores[q] = 1.f / (1.f + expf(-(s + b2[0])));
    }
    __syncthreads();
    if (tid == 0)
        __hip_atomic_fetch_add(&bar[2], 1, __ATOMIC_RELEASE, __HIP_MEMORY_SCOPE_AGENT);
    if (bid != 0) return;

    // ---- block 0: wait for all 637 score blocks (relaxed poll, one acquire) ----
    if (tid == 0) {
        while (__hip_atomic_load(&bar[2], __ATOMIC_RELAXED, __HIP_MEMORY_SCOPE_AGENT) < 637)
            __builtin_amdgcn_s_sleep(8);
        (void)__hip_atomic_load(&bar[2], __ATOMIC_ACQUIRE, __HIP_MEMORY_SCOPE_AGENT);
    }
    __syncthreads();

    // ---- NMS (R9-verified 256-thread version) ----
    {
        unsigned long long* key = (unsigned long long*)smf;          // 20384 B
        float* ss = (float*)(smf + 20384);                           // 10192 B
        float* ee = (float*)(smf + 30576);                           // 10192 B
        unsigned char* st = (unsigned char*)(smf + 40768);           // 2560 B
        unsigned long long* wm0 = (unsigned long long*)(smf + 43328);
        unsigned long long* wm1 = (unsigned long long*)(smf + 43360);
        __shared__ int sh_keeper, keepq[5];
        __shared__ float sh_s0, sh_e0;

        float delta = (float)(*durp) / 128.f;
        for (int i = tid; i < MASKM; i += 256) {
            unsigned sb = __float_as_uint(scores[i]);
            key[i] = ((unsigned long long)sb << 32) | (unsigned)(4095 - i);
            ss[i] = qi[i] * delta;
            ee[i] = (qj[i] + 1) * delta;
            st[i] = 0;
        }
        __syncthreads();
        for (int round = 0; round < 5; ++round) {
            unsigned long long b0 = 0, b1 = 0;
            for (int i = tid; i < MASKM; i += 256) {
                unsigned char s = st[i];
                unsigned long long k = key[i];
                if (s == 0) { if (k > b0) b0 = k; }
                else if (s == 1) { if (k > b1) b1 = k; }
            }
            for (int o = 32; o; o >>= 1) {
                unsigned lo0 = __shfl_down((unsigned)b0, o, 64);
                unsigned hi0 = __shfl_down((unsigned)(b0 >> 32), o, 64);
                unsigned long long u0 = ((unsigned long long)hi0 << 32) | lo0;
                unsigned lo1 = __shfl_down((unsigned)b1, o, 64);
                unsigned hi1 = __shfl_down((unsigned)(b1 >> 32), o, 64);
                unsigned long long u1 = ((unsigned long long)hi1 << 32) | lo1;
                if (u0 > b0) b0 = u0;
                if (u1 > b1) b1 = u1;
            }
            if ((tid & 63) == 0) { wm0[tid >> 6] = b0; wm1[tid >> 6] = b1; }
            __syncthreads();
            if (tid == 0) {
                unsigned long long B0 = 0, B1 = 0;
                for (int w = 0; w < 4; ++w) {
                    if (wm0[w] > B0) B0 = wm0[w];
                    if (wm1[w] > B1) B1 = wm1[w];
                }
                int keeper = (B0 != 0);
                unsigned long long B = keeper ? B0 : B1;
                int q = 4095 - (int)(B & 0xFFFFFFFFull);
                st[q] = keeper ? 2 : 3;
                sh_keeper = keeper;
                sh_s0 = ss[q]; sh_e0 = ee[q];
                keepq[round] = q;
            }
            __syncthreads();
            if (sh_keeper) {
                float s0 = sh_s0, e0 = sh_e0;
                for (int i = tid; i < MASKM; i += 256) {
                    if (st[i] == 0) {
                        float inter = fminf(ee[i], e0) - fmaxf(ss[i], s0);
                        if (inter > 0.f) {
                            float uni = fmaxf(ee[i], e0) - fminf(ss[i], s0);
                            if (inter / uni > 0.5f) st[i] = 1;
                        }
                    }
                }
            }
            __syncthreads();
        }
        if (tid < 5) { out[tid * 2] = ss[keepq[tid]]; out[tid * 2 + 1] = ee[keepq[tid]]; }
    }
}

// ---------------- launch ----------------
extern "C" void kernel_launch(void* const* d_in, const int* in_sizes, int n_in,
                              void* d_out, int out_size, void* d_ws, size_t ws_size,
                              hipStream_t stream) {
    const float* fea   = (const float*)d_in[0];
    const int*   dur   = (const int*)d_in[1];
    const float* w1    = (const float*)d_in[2];
    const float* gamma = (const float*)d_in[3];
    const float* beta  = (const float*)d_in[4];
    const float* w2    = (const float*)d_in[5];
    const float* b2    = (const float*)d_in[6];
    float* out = (float*)d_out;

    char* ws = (char*)d_ws;
    int*    qi     = (int*)(ws + OFF_QI);
    int*    qj     = (int*)(ws + OFF_QJ);
    int*    qidx   = (int*)(ws + OFF_QIDX);
    int*    apix   = (int*)(ws + OFF_APIX);
    int*    bar    = (int*)(ws + OFF_BAR);
    double* part   = (double*)(ws + OFF_PART);
    float*  scores = (float*)(ws + OFF_SC);
    float*  hm     = (float*)(ws + OFF_HM);
    unsigned short* AhU = (unsigned short*)(ws + OFF_AH);
    unsigned short* AlU = (unsigned short*)(ws + OFF_AL);
    unsigned short* BhU = (unsigned short*)(ws + OFF_BH);
    unsigned short* BlU = (unsigned short*)(ws + OFF_BL);
    float*  Yt     = (float*)(ws + OFF_YT);

    static bool attr_set = false;
    if (!attr_set) {
        hipFuncSetAttribute((const void*)k_prep,
                            hipFuncAttributeMaxDynamicSharedMemorySize, PREP_LDS);
        hipFuncSetAttribute((const void*)k_gemm,
                            hipFuncAttributeMaxDynamicSharedMemorySize, 2 * BUFSZ);
        hipFuncSetAttribute((const void*)k_scorenms,
                            hipFuncAttributeMaxDynamicSharedMemorySize, SNMS_LDS);
        attr_set = true;
    }

    k_prep<<<256, 256, PREP_LDS, stream>>>(fea, w1, qi, qj, qidx, apix, part, bar,
                                           AhU, AlU, BhU, BlU);
    k_gemm<<<216, 512, 2 * BUFSZ, stream>>>(AhU, AlU, BhU, BlU, Yt);
    k_gather<<<512, 256, 0, stream>>>(Yt, qidx, apix, hm, part);
    k_scorenms<<<637, 256, SNMS_LDS, stream>>>(hm, part, gamma, beta, w2, b2,
                                               scores, qi, qj, dur, bar, out);
}

// Round 11
// 265.465 us; speedup vs baseline: 2.4073x; 1.0304x over previous
//
#include <hip/hip_runtime.h>
#include <math.h>

// ---------------- problem constants ----------------
#define NPIX 128
#define MASKM 2548
#define NPAD 2560          // padded q count (20*128)
#define MG   6912          // GEMM M = 9 taps * 768
#define KD   768

typedef __attribute__((ext_vector_type(8))) short bf16x8;
typedef __attribute__((ext_vector_type(4))) float f32x4;
typedef __attribute__((ext_vector_type(16))) float f32x16;
typedef __attribute__((ext_vector_type(8))) unsigned short ushort8;

// ---------------- workspace layout ----------------
static constexpr size_t OFF_QI   = 0;
static constexpr size_t OFF_QJ   = OFF_QI + NPAD * 4;
static constexpr size_t OFF_QIDX = OFF_QJ + NPAD * 4;
static constexpr size_t OFF_APIX = OFF_QIDX + 16384 * 4;
static constexpr size_t OFF_BAR  = OFF_APIX + 16384 * 4;   // 4 ints (sync counters)
static constexpr size_t OFF_PART = OFF_BAR + 128 * 4;
static constexpr size_t OFF_SC   = OFF_PART + 512 * 8 * 8;
static constexpr size_t OFF_HM   = OFF_SC + NPAD * 4;
static constexpr size_t OFF_AH   = OFF_HM + (size_t)MASKM * KD * 4;
static constexpr size_t OFF_AL   = OFF_AH + (size_t)MG * KD * 2;
static constexpr size_t OFF_BH   = OFF_AL + (size_t)MG * KD * 2;
static constexpr size_t OFF_BL   = OFF_BH + (size_t)NPAD * KD * 2;
static constexpr size_t OFF_YT   = OFF_BL + (size_t)NPAD * KD * 2;

// ---------------- bf16 hi/lo split helpers ----------------
__device__ __forceinline__ unsigned short f2bf(float f) {
    unsigned u = __float_as_uint(f);
    u = u + 0x7FFFu + ((u >> 16) & 1u);       // RNE
    return (unsigned short)(u >> 16);
}
__device__ __forceinline__ float bf2f(unsigned short h) {
    return __uint_as_float(((unsigned)h) << 16);
}

// ---------------- mask structure (closed form) ----------------
__device__ __forceinline__ bool mask_allowed(int i, int d) {
    if (d == 0) return true;
    if (d <= 15) return true;
    if (d <= 31) return (d >= 17) && ((d & 1) == 1) && ((i & 1) == 0);
    if (d <= 63) return (d >= 35) && ((d & 3) == 3) && ((i & 3) == 0);
    return (d >= 71) && ((d & 7) == 7) && ((i & 7) == 0);
}
__device__ __forceinline__ bool masked_ij(int i, int j) {
    return (j >= i) && (j < NPIX) && (i >= 0) && mask_allowed(i, j - i);
}

// closed-form inverse: rank r within row i -> offset d.
__device__ __forceinline__ int rank_to_d(int i, int r) {
    int rem = NPIX - i;
    int c1 = rem < 16 ? rem : 16;
    if (r < c1) return r;
    r -= c1;
    int h2 = (rem - 1) < 31 ? (rem - 1) : 31;
    int c2 = (((i & 1) == 0) && h2 >= 17) ? ((h2 - 17) >> 1) + 1 : 0;
    if (r < c2) return 17 + 2 * r;
    r -= c2;
    int h3 = (rem - 1) < 63 ? (rem - 1) : 63;
    int c3 = (((i & 3) == 0) && h3 >= 35) ? ((h3 - 35) >> 2) + 1 : 0;
    if (r < c3) return 35 + 4 * r;
    r -= c3;
    return 71 + 8 * r;
}

// ================= k_prep: fill(64) | buildB(48) | prepA(144) = 256 blocks ====
// (verified R9/R10)
#define PREP_LDS 66816
#define PASTR 148

__global__ __launch_bounds__(256) void k_prep(const float* __restrict__ fea,
                                              const float* __restrict__ w1,
                                              int* __restrict__ qi, int* __restrict__ qj,
                                              int* __restrict__ qidx, int* __restrict__ apix,
                                              double* __restrict__ part, int* __restrict__ bar,
                                              unsigned short* __restrict__ Ah,
                                              unsigned short* __restrict__ Al,
                                              unsigned short* __restrict__ Bh,
                                              unsigned short* __restrict__ Bl) {
    extern __shared__ char smp[];
    int tid = threadIdx.x;
    int bid = blockIdx.x;

    if (bid < 64) {
        // ---------------- FILL ----------------
        int* cnt = (int*)smp;
        int* startv = cnt + NPIX;
        if (tid < NPIX) {
            int c = 0;
            for (int d = 0; tid + d < NPIX; ++d) if (mask_allowed(tid, d)) ++c;
            cnt[tid] = c;
        }
        __syncthreads();
        if (tid == 0) {
            int s = 0;
            for (int r = 0; r < NPIX; ++r) { startv[r] = s; s += cnt[r]; }
        }
        __syncthreads();
        int p = bid * 256 + tid;
        int i = p >> 7, j = p & 127;
        int q = -1;
        if (masked_ij(i, j)) {
            int d = j - i, r = 0;
            for (int dd = 0; dd < d; ++dd) r += mask_allowed(i, dd) ? 1 : 0;
            q = startv[i] + r;
            qi[q] = i; qj[q] = j;
        }
        qidx[p] = q;
        int act = 0;
        #pragma unroll
        for (int dy = -1; dy <= 1; ++dy)
            #pragma unroll
            for (int dx = -1; dx <= 1; ++dx)
                if (masked_ij(i + dy, j + dx)) act = 1;
        apix[p] = act;
        if (bid == 0) {
            if (tid < 8) part[tid] = 0.0;
            if (tid >= 8 && tid < 12) bar[tid - 8] = 0;
        }
    } else if (bid < 112) {
        // ---------------- BUILD B (16 channels) ----------------
        float* tab = (float*)smp;                       // [c 16][lvl 8][x 128]
        int* cnt = (int*)(smp + 65536);
        int* startv = (int*)(smp + 66048);              // 129 ints
        int cb = bid - 64, c0 = cb * 16;
        if (tid < NPIX) {
            int c = 0;
            for (int d = 0; tid + d < NPIX; ++d) if (mask_allowed(tid, d)) ++c;
            cnt[tid] = c;
        }
        __syncthreads();
        if (tid == 0) {
            int s = 0;
            for (int r = 0; r < NPIX; ++r) { startv[r] = s; s += cnt[r]; }
            startv[NPIX] = s;
        }
        for (int idx = tid; idx < 16 * NPIX; idx += 256) {
            int c = idx >> 7, x = idx & 127;
            tab[(c * 8) * 128 + x] = fea[(size_t)(c0 + c) * NPIX + x];
        }
        __syncthreads();
        for (int lvl = 1; lvl < 8; ++lvl) {
            int half = 1 << (lvl - 1), full = 1 << lvl;
            for (int idx = tid; idx < 16 * NPIX; idx += 256) {
                int c = idx >> 7, x = idx & 127;
                if (x + full <= NPIX)
                    tab[(c * 8 + lvl) * 128 + x] =
                        fmaxf(tab[(c * 8 + lvl - 1) * 128 + x],
                              tab[(c * 8 + lvl - 1) * 128 + x + half]);
            }
            __syncthreads();
        }
        for (int q = tid; q < NPAD; q += 256) {
            ushort8 vh0 = {}, vh1 = {}, vl0 = {}, vl1 = {};
            if (q < MASKM) {
                int i = 0;
                #pragma unroll
                for (int s = 64; s >= 1; s >>= 1) {
                    int cand = i + s;
                    if (cand <= 127 && startv[cand] <= q) i = cand;
                }
                int d = rank_to_d(i, q - startv[i]);
                int j = i + d;
                int len = d + 1;
                int lvl = 31 - __clz(len);
                int x2 = j + 1 - (1 << lvl);
                #pragma unroll
                for (int c = 0; c < 8; ++c) {
                    float v = fmaxf(tab[(c * 8 + lvl) * 128 + i], tab[(c * 8 + lvl) * 128 + x2]);
                    unsigned short hh = f2bf(v);
                    vh0[c] = hh; vl0[c] = f2bf(v - bf2f(hh));
                }
                #pragma unroll
                for (int c = 0; c < 8; ++c) {
                    float v = fmaxf(tab[((c + 8) * 8 + lvl) * 128 + i], tab[((c + 8) * 8 + lvl) * 128 + x2]);
                    unsigned short hh = f2bf(v);
                    vh1[c] = hh; vl1[c] = f2bf(v - bf2f(hh));
                }
            }
            *(ushort8*)(Bh + (size_t)q * KD + c0)     = vh0;
            *(ushort8*)(Bh + (size_t)q * KD + c0 + 8) = vh1;
            *(ushort8*)(Bl + (size_t)q * KD + c0)     = vl0;
            *(ushort8*)(Bl + (size_t)q * KD + c0 + 8) = vl1;
        }
    } else {
        // ---------------- PREP A ----------------
        float* tile = (float*)smp;
        int pb = bid - 112;
        int co0 = (pb % 12) * 64, ci0 = (pb / 12) * 64;
        for (int s = 0; s < 4; ++s) {
            int cib = ci0 + s * 16;
            __syncthreads();
            for (int idx = tid; idx < 2304; idx += 256) {
                int row = idx / 36, c4 = idx % 36;
                float4 v = *(const float4*)(w1 + (size_t)(co0 + row) * MG + cib * 9 + c4 * 4);
                *(float4*)&tile[row * PASTR + c4 * 4] = v;
            }
            __syncthreads();
            for (int idx = tid; idx < 1152; idx += 256) {
                int tap = idx / 128;
                int rem = idx - tap * 128;
                int co = rem >> 1, half = rem & 1;
                ushort8 vh, vl;
                #pragma unroll
                for (int c = 0; c < 8; ++c) {
                    float v = tile[co * PASTR + (half * 8 + c) * 9 + tap];
                    unsigned short hi = f2bf(v);
                    vh[c] = hi;
                    vl[c] = f2bf(v - bf2f(hi));
                }
                size_t ob = (size_t)(tap * 768 + co0 + co) * KD + cib + half * 8;
                *(ushort8*)(Ah + ob) = vh;
                *(ushort8*)(Al + ob) = vl;
            }
        }
    }
}

// ---------------- bf16x3 MFMA GEMM: Yt[n][m] = sum_k A[m][k] * B[n][k] ----------
// 32x32x16 MFMA, BM=256 BN=320 BK=32, grid 216 = 8 XCD x 27 (one round).
// Chunk-major LDS slots (0 bank conflicts). R11: m201-style FINE PHASES.
// Pipe audit (R10): MFMA 3874 cyc/tile || LDS reads 2634 + stage-writes 867 =
// 3501 cyc/tile; measured 9600 -> pipes run back-to-back (convoy). R2 had phase
// barriers but 4.6M bank conflicts; R4/R7 conflict-free but coarse clusters.
// This combines both: 4 phases/tile, each {reads + 2-3 stages | raw s_barrier |
// setprio MFMA cluster | raw s_barrier}. Raw barriers carry NO waitcnt (reads
// are register-dep tracked; NB slots only read after tile-end __syncthreads,
// whose vmcnt(0) drains stages issued ~8000 cyc earlier -> free). Stages spread
// 3/2/2/2 across phases. Max 10 live frags = 40 VGPR (no spill; R5 lesson).
#define BUFSZ   73728      // Ah(16K) | Al(16K) | Bh(20K) | Bl(20K)
#define SB_BH   32768

__global__ __launch_bounds__(512, 1) void k_gemm(const unsigned short* __restrict__ Ah,
                                                 const unsigned short* __restrict__ Al,
                                                 const unsigned short* __restrict__ Bh,
                                                 const unsigned short* __restrict__ Bl,
                                                 float* __restrict__ Yt) {
    extern __shared__ char sm[];               // 2 * BUFSZ = 144 KB dynamic LDS
    int tid = threadIdx.x;
    int wave = tid >> 6, lane = tid & 63;

    int bid = (int)blockIdx.x;
    int xcd = bid & 7, loc = bid >> 3;         // 8 XCDs x 27 M-tiles
    int m0 = loc * 256, n0 = xcd * 320;

    int wm = (wave & 3) << 6, wn = (wave >> 2) * 160;
    int r32 = lane & 31, hi2 = lane >> 5;
    int rb  = (r32 >> 4) * 1024 + hi2 * 256 + (r32 & 15) * 16;
    int awb = (wm >> 4) * 1024 + rb;
    int bwb = (wn >> 4) * 1024 + rb;

    int lrow = lane & 15, lchk = lane >> 4;
    const unsigned short* sp[9];
    int so[9];
    #pragma unroll
    for (int s = 0; s < 9; ++s) {
        int gid = wave * 9 + s;
        const unsigned short* base;
        int row0, ldso;
        if (gid < 16)      { base = Ah; row0 = m0 + gid * 16;        ldso = gid * 1024; }
        else if (gid < 32) { base = Al; row0 = m0 + (gid - 16) * 16; ldso = 16384 + (gid - 16) * 1024; }
        else if (gid < 52) { base = Bh; row0 = n0 + (gid - 32) * 16; ldso = SB_BH + (gid - 32) * 1024; }
        else               { base = Bl; row0 = n0 + (gid - 52) * 16; ldso = SB_BH + 20480 + (gid - 52) * 1024; }
        sp[s] = base + (size_t)(row0 + lrow) * KD + lchk * 8;
        so[s] = ldso;
    }

    f32x16 acc[2][5] = {};
    char* CB = sm;
    char* NB = sm + BUFSZ;

    #define STAGE(DST, s, koff) __builtin_amdgcn_global_load_lds( \
        (const __attribute__((address_space(1))) unsigned int*)(sp[s] + (koff)), \
        (__attribute__((address_space(3))) unsigned int*)((DST) + so[s]), 16, 0, 0)
    #define ARD(hl, mf, ks) (*(const bf16x8*)(CB + (hl) * 16384 + awb + (mf) * 2048 + (ks) * 512))
    #define BRD(hl, nf, ks) (*(const bf16x8*)(CB + SB_BH + (hl) * 20480 + bwb + (nf) * 2048 + (ks) * 512))
    #define TRIP(mf, nf, xh, xl, yh, yl) \
        acc[mf][nf] = __builtin_amdgcn_mfma_f32_32x32x16_bf16(xh, yh, acc[mf][nf], 0, 0, 0); \
        acc[mf][nf] = __builtin_amdgcn_mfma_f32_32x32x16_bf16(xh, yl, acc[mf][nf], 0, 0, 0); \
        acc[mf][nf] = __builtin_amdgcn_mfma_f32_32x32x16_bf16(xl, yh, acc[mf][nf], 0, 0, 0);
    #define RBAR __builtin_amdgcn_s_barrier()

    #pragma unroll
    for (int s = 0; s < 9; ++s) STAGE(CB, s, 0);
    __syncthreads();

    for (int t = 0; t < 24; ++t) {
        int kn = (t + 1) * 32;
        bool stg = (t < 23);
        bf16x8 a0h, a0l, a1h, a1l, bxh, bxl, byh, byl;

        #pragma unroll
        for (int ks = 0; ks < 2; ++ks) {
            // ---- phase A (12 MFMA): reads A(ks), B0, B1 ----
            a0h = ARD(0, 0, ks); a0l = ARD(1, 0, ks);
            a1h = ARD(0, 1, ks); a1l = ARD(1, 1, ks);
            bxh = BRD(0, 0, ks); bxl = BRD(1, 0, ks);
            byh = BRD(0, 1, ks); byl = BRD(1, 1, ks);
            if (stg) {
                if (ks == 0) { STAGE(NB, 0, kn); STAGE(NB, 1, kn); STAGE(NB, 2, kn); }
                else         { STAGE(NB, 5, kn); STAGE(NB, 6, kn); }
            }
            RBAR;
            __builtin_amdgcn_s_setprio(1);
            TRIP(0, 0, a0h, a0l, bxh, bxl)
            TRIP(1, 0, a1h, a1l, bxh, bxl)
            TRIP(0, 1, a0h, a0l, byh, byl)
            TRIP(1, 1, a1h, a1l, byh, byl)
            __builtin_amdgcn_s_setprio(0);
            RBAR;

            // ---- phase B (18 MFMA): reads B2, B3, B4 ----
            bxh = BRD(0, 2, ks); bxl = BRD(1, 2, ks);
            byh = BRD(0, 3, ks); byl = BRD(1, 3, ks);
            bf16x8 bzh = BRD(0, 4, ks), bzl = BRD(1, 4, ks);
            if (stg) {
                if (ks == 0) { STAGE(NB, 3, kn); STAGE(NB, 4, kn); }
                else         { STAGE(NB, 7, kn); STAGE(NB, 8, kn); }
            }
            RBAR;
            __builtin_amdgcn_s_setprio(1);
            TRIP(0, 2, a0h, a0l, bxh, bxl)
            TRIP(1, 2, a1h, a1l, bxh, bxl)
            TRIP(0, 3, a0h, a0l, byh, byl)
            TRIP(1, 3, a1h, a1l, byh, byl)
            TRIP(0, 4, a0h, a0l, bzh, bzl)
            TRIP(1, 4, a1h, a1l, bzh, bzl)
            __builtin_amdgcn_s_setprio(0);
            if (ks == 0) RBAR;
            // (ks==1 phase-B end barrier = the tile-end __syncthreads below)
        }

        // tile boundary: vmcnt(0)+lgkmcnt(0) drain (stages for t+1 resident)
        // and buffer-swap gate.
        __syncthreads();
        char* tmp = CB; CB = NB; NB = tmp;
    }

    #pragma unroll
    for (int mf = 0; mf < 2; ++mf)
        #pragma unroll
        for (int nf = 0; nf < 5; ++nf) {
            int n = n0 + wn + nf * 32 + r32;
            size_t rowb = (size_t)n * MG + m0 + wm + mf * 32 + 4 * hi2;
            #pragma unroll
            for (int g = 0; g < 4; ++g) {
                f32x4 v = { acc[mf][nf][g * 4 + 0], acc[mf][nf][g * 4 + 1],
                            acc[mf][nf][g * 4 + 2], acc[mf][nf][g * 4 + 3] };
                *(f32x4*)(Yt + rowb + 8 * g) = v;
            }
        }
    #undef STAGE
    #undef ARD
    #undef BRD
    #undef TRIP
    #undef RBAR
}

// ---------------- gather taps -> hm + GN partial sums (R7-proven) ---------------
__global__ __launch_bounds__(256) void k_gather(const float* __restrict__ Yt,
                                                const int* __restrict__ qidx,
                                                const int* __restrict__ apix,
                                                float* __restrict__ hm,
                                                double* __restrict__ part) {
    __shared__ double red1[256 * 4], red2[256 * 4];
    int tid = threadIdx.x;
    int wave = tid >> 6, lane = tid & 63;
    double a1[3] = {0, 0, 0}, a2[3] = {0, 0, 0};
    int gs[3];
    #pragma unroll
    for (int s = 0; s < 3; ++s) gs[s] = (64 * s + lane) / 48;

    for (int it = 0; it < 8; ++it) {
        int p = blockIdx.x * 32 + wave * 8 + it;
        if (!apix[p]) continue;
        int y = p >> 7, x = p & 127;
        float4 hv[3] = {};
        #pragma unroll
        for (int tap = 0; tap < 9; ++tap) {
            int i = y + tap / 3 - 1, j = x + tap % 3 - 1;
            if ((unsigned)i < 128u && (unsigned)j < 128u) {
                int q = qidx[i * NPIX + j];
                if (q >= 0) {
                    const float* yr = Yt + (size_t)q * MG + tap * 768 + lane * 4;
                    #pragma unroll
                    for (int s = 0; s < 3; ++s) {
                        float4 v = *(const float4*)(yr + s * 256);
                        hv[s].x += v.x; hv[s].y += v.y; hv[s].z += v.z; hv[s].w += v.w;
                    }
                }
            }
        }
        int qp = qidx[p];
        if (qp >= 0) {
            #pragma unroll
            for (int s = 0; s < 3; ++s)
                *(float4*)(hm + (size_t)qp * KD + s * 256 + lane * 4) = hv[s];
        }
        #pragma unroll
        for (int s = 0; s < 3; ++s) {
            a1[s] += (double)hv[s].x + (double)hv[s].y + (double)hv[s].z + (double)hv[s].w;
            a2[s] += (double)hv[s].x * hv[s].x + (double)hv[s].y * hv[s].y +
                     (double)hv[s].z * hv[s].z + (double)hv[s].w * hv[s].w;
        }
    }
    #pragma unroll
    for (int g = 0; g < 4; ++g) { red1[tid * 4 + g] = 0.0; red2[tid * 4 + g] = 0.0; }
    #pragma unroll
    for (int s = 0; s < 3; ++s) { red1[tid * 4 + gs[s]] = a1[s]; red2[tid * 4 + gs[s]] = a2[s]; }
    __syncthreads();
    if (tid < 8) {
        int g = tid & 3;
        double s = 0.0;
        if (tid < 4) { for (int i = 0; i < 256; ++i) s += red1[i * 4 + g]; }
        else         { for (int i = 0; i < 256; ++i) s += red2[i * 4 + g]; }
        atomicAdd(&part[tid], s);
    }
}

// ================= k_scorenms (R10-proven: relaxed-poll single consumer) =======
#define SNMS_LDS 44544

__global__ __launch_bounds__(256) void k_scorenms(const float* __restrict__ hm,
                                                  const double* __restrict__ part,
                                                  const float* __restrict__ gamma,
                                                  const float* __restrict__ beta,
                                                  const float* __restrict__ w2,
                                                  const float* __restrict__ b2,
                                                  float* __restrict__ scores,
                                                  const int* __restrict__ qi,
                                                  const int* __restrict__ qj,
                                                  const int* __restrict__ durp,
                                                  int* __restrict__ bar,
                                                  float* __restrict__ out) {
    extern __shared__ char smf[];
    int tid = threadIdx.x;
    int bid = (int)blockIdx.x;
    int lane = tid & 63;

    {
        float mu[4], rs[4];
        const double cnt = 192.0 * 16384.0;
        #pragma unroll
        for (int g = 0; g < 4; ++g) {
            double m = part[g] / cnt;
            double v = part[4 + g] / cnt - m * m;
            mu[g] = (float)m;
            rs[g] = (float)(1.0 / sqrt(v + 1e-5));
        }
        int q = bid * 4 + (tid >> 6);
        const float* hp = hm + (size_t)q * KD;
        float s = 0.f;
        for (int c = lane; c < KD; c += 64) {
            int g = c / 192;
            float v = (hp[c] - mu[g]) * rs[g] * gamma[c] + beta[c];
            s += fmaxf(v, 0.f) * w2[c];
        }
        for (int o = 32; o; o >>= 1) s += __shfl_down(s, o, 64);
        if (lane == 0) scores[q] = 1.f / (1.f + expf(-(s + b2[0])));
    }
    __syncthreads();
    if (tid == 0)
        __hip_atomic_fetch_add(&bar[2], 1, __ATOMIC_RELEASE, __HIP_MEMORY_SCOPE_AGENT);
    if (bid != 0) return;

    if (tid == 0) {
        while (__hip_atomic_load(&bar[2], __ATOMIC_RELAXED, __HIP_MEMORY_SCOPE_AGENT) < 637)
            __builtin_amdgcn_s_sleep(8);
        (void)__hip_atomic_load(&bar[2], __ATOMIC_ACQUIRE, __HIP_MEMORY_SCOPE_AGENT);
    }
    __syncthreads();

    {
        unsigned long long* key = (unsigned long long*)smf;
        float* ss = (float*)(smf + 20384);
        float* ee = (float*)(smf + 30576);
        unsigned char* st = (unsigned char*)(smf + 40768);
        unsigned long long* wm0 = (unsigned long long*)(smf + 43328);
        unsigned long long* wm1 = (unsigned long long*)(smf + 43360);
        __shared__ int sh_keeper, keepq[5];
        __shared__ float sh_s0, sh_e0;

        float delta = (float)(*durp) / 128.f;
        for (int i = tid; i < MASKM; i += 256) {
            unsigned sb = __float_as_uint(scores[i]);
            key[i] = ((unsigned long long)sb << 32) | (unsigned)(4095 - i);
            ss[i] = qi[i] * delta;
            ee[i] = (qj[i] + 1) * delta;
            st[i] = 0;
        }
        __syncthreads();
        for (int round = 0; round < 5; ++round) {
            unsigned long long b0 = 0, b1 = 0;
            for (int i = tid; i < MASKM; i += 256) {
                unsigned char s = st[i];
                unsigned long long k = key[i];
                if (s == 0) { if (k > b0) b0 = k; }
                else if (s == 1) { if (k > b1) b1 = k; }
            }
            for (int o = 32; o; o >>= 1) {
                unsigned lo0 = __shfl_down((unsigned)b0, o, 64);
                unsigned hi0 = __shfl_down((unsigned)(b0 >> 32), o, 64);
                unsigned long long u0 = ((unsigned long long)hi0 << 32) | lo0;
                unsigned lo1 = __shfl_down((unsigned)b1, o, 64);
                unsigned hi1 = __shfl_down((unsigned)(b1 >> 32), o, 64);
                unsigned long long u1 = ((unsigned long long)hi1 << 32) | lo1;
                if (u0 > b0) b0 = u0;
                if (u1 > b1) b1 = u1;
            }
            if ((tid & 63) == 0) { wm0[tid >> 6] = b0; wm1[tid >> 6] = b1; }
            __syncthreads();
            if (tid == 0) {
                unsigned long long B0 = 0, B1 = 0;
                for (int w = 0; w < 4; ++w) {
                    if (wm0[w] > B0) B0 = wm0[w];
                    if (wm1[w] > B1) B1 = wm1[w];
                }
                int keeper = (B0 != 0);
                unsigned long long B = keeper ? B0 : B1;
                int q = 4095 - (int)(B & 0xFFFFFFFFull);
                st[q] = keeper ? 2 : 3;
                sh_keeper = keeper;
                sh_s0 = ss[q]; sh_e0 = ee[q];
                keepq[round] = q;
            }
            __syncthreads();
            if (sh_keeper) {
                float s0 = sh_s0, e0 = sh_e0;
                for (int i = tid; i < MASKM; i += 256) {
                    if (st[i] == 0) {
                        float inter = fminf(ee[i], e0) - fmaxf(ss[i], s0);
                        if (inter > 0.f) {
                            float uni = fmaxf(ee[i], e0) - fminf(ss[i], s0);
                            if (inter / uni > 0.5f) st[i] = 1;
                        }
                    }
                }
            }
            __syncthreads();
        }
        if (tid < 5) { out[tid * 2] = ss[keepq[tid]]; out[tid * 2 + 1] = ee[keepq[tid]]; }
    }
}

// ---------------- launch ----------------
extern "C" void kernel_launch(void* const* d_in, const int* in_sizes, int n_in,
                              void* d_out, int out_size, void* d_ws, size_t ws_size,
                              hipStream_t stream) {
    const float* fea   = (const float*)d_in[0];
    const int*   dur   = (const int*)d_in[1];
    const float* w1    = (const float*)d_in[2];
    const float* gamma = (const float*)d_in[3];
    const float* beta  = (const float*)d_in[4];
    const float* w2    = (const float*)d_in[5];
    const float* b2    = (const float*)d_in[6];
    float* out = (float*)d_out;

    char* ws = (char*)d_ws;
    int*    qi     = (int*)(ws + OFF_QI);
    int*    qj     = (int*)(ws + OFF_QJ);
    int*    qidx   = (int*)(ws + OFF_QIDX);
    int*    apix   = (int*)(ws + OFF_APIX);
    int*    bar    = (int*)(ws + OFF_BAR);
    double* part   = (double*)(ws + OFF_PART);
    float*  scores = (float*)(ws + OFF_SC);
    float*  hm     = (float*)(ws + OFF_HM);
    unsigned short* AhU = (unsigned short*)(ws + OFF_AH);
    unsigned short* AlU = (unsigned short*)(ws + OFF_AL);
    unsigned short* BhU = (unsigned short*)(ws + OFF_BH);
    unsigned short* BlU = (unsigned short*)(ws + OFF_BL);
    float*  Yt     = (float*)(ws + OFF_YT);

    static bool attr_set = false;
    if (!attr_set) {
        hipFuncSetAttribute((const void*)k_prep,
                            hipFuncAttributeMaxDynamicSharedMemorySize, PREP_LDS);
        hipFuncSetAttribute((const void*)k_gemm,
                            hipFuncAttributeMaxDynamicSharedMemorySize, 2 * BUFSZ);
        hipFuncSetAttribute((const void*)k_scorenms,
                            hipFuncAttributeMaxDynamicSharedMemorySize, SNMS_LDS);
        attr_set = true;
    }

    k_prep<<<256, 256, PREP_LDS, stream>>>(fea, w1, qi, qj, qidx, apix, part, bar,
                                           AhU, AlU, BhU, BlU);
    k_gemm<<<216, 512, 2 * BUFSZ, stream>>>(AhU, AlU, BhU, BlU, Yt);
    k_gather<<<512, 256, 0, stream>>>(Yt, qidx, apix, hm, part);
    k_scorenms<<<637, 256, SNMS_LDS, stream>>>(hm, part, gamma, beta, w2, b2,
                                               scores, qi, qj, dur, bar, out);
}

// Round 12
// 260.295 us; speedup vs baseline: 2.4551x; 1.0199x over previous
//
#include <hip/hip_runtime.h>
#include <math.h>

// ---------------- problem constants ----------------
#define NPIX 128
#define MASKM 2548
#define NPAD 2560          // padded q count (20*128)
#define MG   6912          // GEMM M = 9 taps * 768
#define KD   768

typedef __attribute__((ext_vector_type(8))) short bf16x8;
typedef __attribute__((ext_vector_type(4))) float f32x4;
typedef __attribute__((ext_vector_type(16))) float f32x16;
typedef __attribute__((ext_vector_type(8))) unsigned short ushort8;

// ---------------- workspace layout ----------------
static constexpr size_t OFF_QI   = 0;
static constexpr size_t OFF_QJ   = OFF_QI + NPAD * 4;
static constexpr size_t OFF_QIDX = OFF_QJ + NPAD * 4;
static constexpr size_t OFF_APIX = OFF_QIDX + 16384 * 4;
static constexpr size_t OFF_BAR  = OFF_APIX + 16384 * 4;   // 4 ints (sync counters)
static constexpr size_t OFF_PART = OFF_BAR + 128 * 4;
static constexpr size_t OFF_SC   = OFF_PART + 512 * 8 * 8;
static constexpr size_t OFF_HM   = OFF_SC + NPAD * 4;
static constexpr size_t OFF_AH   = OFF_HM + (size_t)MASKM * KD * 4;
static constexpr size_t OFF_AL   = OFF_AH + (size_t)MG * KD * 2;
static constexpr size_t OFF_BH   = OFF_AL + (size_t)MG * KD * 2;
static constexpr size_t OFF_BL   = OFF_BH + (size_t)NPAD * KD * 2;
static constexpr size_t OFF_YT   = OFF_BL + (size_t)NPAD * KD * 2;

// ---------------- bf16 hi/lo split helpers ----------------
__device__ __forceinline__ unsigned short f2bf(float f) {
    unsigned u = __float_as_uint(f);
    u = u + 0x7FFFu + ((u >> 16) & 1u);       // RNE
    return (unsigned short)(u >> 16);
}
__device__ __forceinline__ float bf2f(unsigned short h) {
    return __uint_as_float(((unsigned)h) << 16);
}

// ---------------- mask structure (closed form) ----------------
__device__ __forceinline__ bool mask_allowed(int i, int d) {
    if (d == 0) return true;
    if (d <= 15) return true;
    if (d <= 31) return (d >= 17) && ((d & 1) == 1) && ((i & 1) == 0);
    if (d <= 63) return (d >= 35) && ((d & 3) == 3) && ((i & 3) == 0);
    return (d >= 71) && ((d & 7) == 7) && ((i & 7) == 0);
}
__device__ __forceinline__ bool masked_ij(int i, int j) {
    return (j >= i) && (j < NPIX) && (i >= 0) && mask_allowed(i, j - i);
}

// closed-form inverse: rank r within row i -> offset d.
__device__ __forceinline__ int rank_to_d(int i, int r) {
    int rem = NPIX - i;
    int c1 = rem < 16 ? rem : 16;
    if (r < c1) return r;
    r -= c1;
    int h2 = (rem - 1) < 31 ? (rem - 1) : 31;
    int c2 = (((i & 1) == 0) && h2 >= 17) ? ((h2 - 17) >> 1) + 1 : 0;
    if (r < c2) return 17 + 2 * r;
    r -= c2;
    int h3 = (rem - 1) < 63 ? (rem - 1) : 63;
    int c3 = (((i & 3) == 0) && h3 >= 35) ? ((h3 - 35) >> 2) + 1 : 0;
    if (r < c3) return 35 + 4 * r;
    r -= c3;
    return 71 + 8 * r;
}

// ================= k_prep: fill(64) | buildB(48) | prepA(144) = 256 blocks ====
// (verified R9/R10)
#define PREP_LDS 66816
#define PASTR 148

__global__ __launch_bounds__(256) void k_prep(const float* __restrict__ fea,
                                              const float* __restrict__ w1,
                                              int* __restrict__ qi, int* __restrict__ qj,
                                              int* __restrict__ qidx, int* __restrict__ apix,
                                              double* __restrict__ part, int* __restrict__ bar,
                                              unsigned short* __restrict__ Ah,
                                              unsigned short* __restrict__ Al,
                                              unsigned short* __restrict__ Bh,
                                              unsigned short* __restrict__ Bl) {
    extern __shared__ char smp[];
    int tid = threadIdx.x;
    int bid = blockIdx.x;

    if (bid < 64) {
        // ---------------- FILL ----------------
        int* cnt = (int*)smp;
        int* startv = cnt + NPIX;
        if (tid < NPIX) {
            int c = 0;
            for (int d = 0; tid + d < NPIX; ++d) if (mask_allowed(tid, d)) ++c;
            cnt[tid] = c;
        }
        __syncthreads();
        if (tid == 0) {
            int s = 0;
            for (int r = 0; r < NPIX; ++r) { startv[r] = s; s += cnt[r]; }
        }
        __syncthreads();
        int p = bid * 256 + tid;
        int i = p >> 7, j = p & 127;
        int q = -1;
        if (masked_ij(i, j)) {
            int d = j - i, r = 0;
            for (int dd = 0; dd < d; ++dd) r += mask_allowed(i, dd) ? 1 : 0;
            q = startv[i] + r;
            qi[q] = i; qj[q] = j;
        }
        qidx[p] = q;
        int act = 0;
        #pragma unroll
        for (int dy = -1; dy <= 1; ++dy)
            #pragma unroll
            for (int dx = -1; dx <= 1; ++dx)
                if (masked_ij(i + dy, j + dx)) act = 1;
        apix[p] = act;
        if (bid == 0) {
            if (tid < 8) part[tid] = 0.0;
            if (tid >= 8 && tid < 12) bar[tid - 8] = 0;
        }
    } else if (bid < 112) {
        // ---------------- BUILD B (16 channels) ----------------
        float* tab = (float*)smp;                       // [c 16][lvl 8][x 128]
        int* cnt = (int*)(smp + 65536);
        int* startv = (int*)(smp + 66048);              // 129 ints
        int cb = bid - 64, c0 = cb * 16;
        if (tid < NPIX) {
            int c = 0;
            for (int d = 0; tid + d < NPIX; ++d) if (mask_allowed(tid, d)) ++c;
            cnt[tid] = c;
        }
        __syncthreads();
        if (tid == 0) {
            int s = 0;
            for (int r = 0; r < NPIX; ++r) { startv[r] = s; s += cnt[r]; }
            startv[NPIX] = s;
        }
        for (int idx = tid; idx < 16 * NPIX; idx += 256) {
            int c = idx >> 7, x = idx & 127;
            tab[(c * 8) * 128 + x] = fea[(size_t)(c0 + c) * NPIX + x];
        }
        __syncthreads();
        for (int lvl = 1; lvl < 8; ++lvl) {
            int half = 1 << (lvl - 1), full = 1 << lvl;
            for (int idx = tid; idx < 16 * NPIX; idx += 256) {
                int c = idx >> 7, x = idx & 127;
                if (x + full <= NPIX)
                    tab[(c * 8 + lvl) * 128 + x] =
                        fmaxf(tab[(c * 8 + lvl - 1) * 128 + x],
                              tab[(c * 8 + lvl - 1) * 128 + x + half]);
            }
            __syncthreads();
        }
        for (int q = tid; q < NPAD; q += 256) {
            ushort8 vh0 = {}, vh1 = {}, vl0 = {}, vl1 = {};
            if (q < MASKM) {
                int i = 0;
                #pragma unroll
                for (int s = 64; s >= 1; s >>= 1) {
                    int cand = i + s;
                    if (cand <= 127 && startv[cand] <= q) i = cand;
                }
                int d = rank_to_d(i, q - startv[i]);
                int j = i + d;
                int len = d + 1;
                int lvl = 31 - __clz(len);
                int x2 = j + 1 - (1 << lvl);
                #pragma unroll
                for (int c = 0; c < 8; ++c) {
                    float v = fmaxf(tab[(c * 8 + lvl) * 128 + i], tab[(c * 8 + lvl) * 128 + x2]);
                    unsigned short hh = f2bf(v);
                    vh0[c] = hh; vl0[c] = f2bf(v - bf2f(hh));
                }
                #pragma unroll
                for (int c = 0; c < 8; ++c) {
                    float v = fmaxf(tab[((c + 8) * 8 + lvl) * 128 + i], tab[((c + 8) * 8 + lvl) * 128 + x2]);
                    unsigned short hh = f2bf(v);
                    vh1[c] = hh; vl1[c] = f2bf(v - bf2f(hh));
                }
            }
            *(ushort8*)(Bh + (size_t)q * KD + c0)     = vh0;
            *(ushort8*)(Bh + (size_t)q * KD + c0 + 8) = vh1;
            *(ushort8*)(Bl + (size_t)q * KD + c0)     = vl0;
            *(ushort8*)(Bl + (size_t)q * KD + c0 + 8) = vl1;
        }
    } else {
        // ---------------- PREP A ----------------
        float* tile = (float*)smp;
        int pb = bid - 112;
        int co0 = (pb % 12) * 64, ci0 = (pb / 12) * 64;
        for (int s = 0; s < 4; ++s) {
            int cib = ci0 + s * 16;
            __syncthreads();
            for (int idx = tid; idx < 2304; idx += 256) {
                int row = idx / 36, c4 = idx % 36;
                float4 v = *(const float4*)(w1 + (size_t)(co0 + row) * MG + cib * 9 + c4 * 4);
                *(float4*)&tile[row * PASTR + c4 * 4] = v;
            }
            __syncthreads();
            for (int idx = tid; idx < 1152; idx += 256) {
                int tap = idx / 128;
                int rem = idx - tap * 128;
                int co = rem >> 1, half = rem & 1;
                ushort8 vh, vl;
                #pragma unroll
                for (int c = 0; c < 8; ++c) {
                    float v = tile[co * PASTR + (half * 8 + c) * 9 + tap];
                    unsigned short hi = f2bf(v);
                    vh[c] = hi;
                    vl[c] = f2bf(v - bf2f(hi));
                }
                size_t ob = (size_t)(tap * 768 + co0 + co) * KD + cib + half * 8;
                *(ushort8*)(Ah + ob) = vh;
                *(ushort8*)(Al + ob) = vl;
            }
        }
    }
}

// ---------------- bf16x3 MFMA GEMM: Yt[n][m] = sum_k A[m][k] * B[n][k] ----------
// 32x32x16 MFMA, BM=256 BN=320 BK=32, grid 216 = 8 XCD x 27 (one round).
// Chunk-major LDS slots (0 bank conflicts). R12: ONE-PHASE-LOOKAHEAD reads.
// R11 (same-phase reads + barriers) = 8780 cyc/tile: LDS drain (2688) serially
// exposed before each cluster (barriers force all-read -> all-MFMA). CB is
// read-only intra-tile, so reads for phase p+1 can be issued BEFORE MFMA(p):
//   [RBAR][reads(p+1)][sched_barrier(0) - prevents read sinking (R7's silent
//   failure)][setprio MFMA cluster(p) - counted lgkm: operands read a phase ago]
// 10 nf-major phases x 6 MFMA + 1 setup phase. LDS drains under MFMA clusters;
// only setup reads (~576cyc) exposed per tile. Max 12 live frags = 48 VGPR.
#define BUFSZ   73728      // Ah(16K) | Al(16K) | Bh(20K) | Bl(20K)
#define SB_BH   32768

__global__ __launch_bounds__(512, 1) void k_gemm(const unsigned short* __restrict__ Ah,
                                                 const unsigned short* __restrict__ Al,
                                                 const unsigned short* __restrict__ Bh,
                                                 const unsigned short* __restrict__ Bl,
                                                 float* __restrict__ Yt) {
    extern __shared__ char sm[];               // 2 * BUFSZ = 144 KB dynamic LDS
    int tid = threadIdx.x;
    int wave = tid >> 6, lane = tid & 63;

    int bid = (int)blockIdx.x;
    int xcd = bid & 7, loc = bid >> 3;         // 8 XCDs x 27 M-tiles
    int m0 = loc * 256, n0 = xcd * 320;

    int wm = (wave & 3) << 6, wn = (wave >> 2) * 160;
    int r32 = lane & 31, hi2 = lane >> 5;
    int rb  = (r32 >> 4) * 1024 + hi2 * 256 + (r32 & 15) * 16;
    int awb = (wm >> 4) * 1024 + rb;
    int bwb = (wn >> 4) * 1024 + rb;

    int lrow = lane & 15, lchk = lane >> 4;
    const unsigned short* sp[9];
    int so[9];
    #pragma unroll
    for (int s = 0; s < 9; ++s) {
        int gid = wave * 9 + s;
        const unsigned short* base;
        int row0, ldso;
        if (gid < 16)      { base = Ah; row0 = m0 + gid * 16;        ldso = gid * 1024; }
        else if (gid < 32) { base = Al; row0 = m0 + (gid - 16) * 16; ldso = 16384 + (gid - 16) * 1024; }
        else if (gid < 52) { base = Bh; row0 = n0 + (gid - 32) * 16; ldso = SB_BH + (gid - 32) * 1024; }
        else               { base = Bl; row0 = n0 + (gid - 52) * 16; ldso = SB_BH + 20480 + (gid - 52) * 1024; }
        sp[s] = base + (size_t)(row0 + lrow) * KD + lchk * 8;
        so[s] = ldso;
    }

    f32x16 acc[2][5] = {};
    char* CB = sm;
    char* NB = sm + BUFSZ;

    #define STAGE(DST, s, koff) __builtin_amdgcn_global_load_lds( \
        (const __attribute__((address_space(1))) unsigned int*)(sp[s] + (koff)), \
        (__attribute__((address_space(3))) unsigned int*)((DST) + so[s]), 16, 0, 0)
    #define ARD(hl, mf, ks) (*(const bf16x8*)(CB + (hl) * 16384 + awb + (mf) * 2048 + (ks) * 512))
    #define BRD(hl, nf, ks) (*(const bf16x8*)(CB + SB_BH + (hl) * 20480 + bwb + (nf) * 2048 + (ks) * 512))
    #define TRIP(mf, nf, xh, xl, yh, yl) \
        acc[mf][nf] = __builtin_amdgcn_mfma_f32_32x32x16_bf16(xh, yh, acc[mf][nf], 0, 0, 0); \
        acc[mf][nf] = __builtin_amdgcn_mfma_f32_32x32x16_bf16(xh, yl, acc[mf][nf], 0, 0, 0); \
        acc[mf][nf] = __builtin_amdgcn_mfma_f32_32x32x16_bf16(xl, yh, acc[mf][nf], 0, 0, 0);
    #define RBAR __builtin_amdgcn_s_barrier()
    #define SB0  __builtin_amdgcn_sched_barrier(0)
    #define CL6(nf, xh0, xl0, xh1, xl1, yh, yl) \
        __builtin_amdgcn_s_setprio(1); \
        TRIP(0, nf, xh0, xl0, yh, yl) \
        TRIP(1, nf, xh1, xl1, yh, yl) \
        __builtin_amdgcn_s_setprio(0);

    #pragma unroll
    for (int s = 0; s < 9; ++s) STAGE(CB, s, 0);
    __syncthreads();

    for (int t = 0; t < 24; ++t) {
        int kn = (t + 1) * 32;
        bool stg = (t < 23);
        bf16x8 a0h, a0l, a1h, a1l;             // A frags, ks0
        bf16x8 c0h, c0l, c1h, c1l;             // A frags, ks1
        bf16x8 bxh, bxl, byh, byl;             // rotating B pairs

        // P0 (setup): reads A(ks0), B0(ks0); stages 0-2
        a0h = ARD(0, 0, 0); a0l = ARD(1, 0, 0);
        a1h = ARD(0, 1, 0); a1l = ARD(1, 1, 0);
        bxh = BRD(0, 0, 0); bxl = BRD(1, 0, 0);
        if (stg) { STAGE(NB, 0, kn); STAGE(NB, 1, kn); STAGE(NB, 2, kn); }
        RBAR;

        // ks0 nf0 | prefetch B1
        byh = BRD(0, 1, 0); byl = BRD(1, 1, 0);
        SB0;
        CL6(0, a0h, a0l, a1h, a1l, bxh, bxl)
        RBAR;
        // ks0 nf1 | prefetch B2
        bxh = BRD(0, 2, 0); bxl = BRD(1, 2, 0);
        SB0;
        CL6(1, a0h, a0l, a1h, a1l, byh, byl)
        RBAR;
        // ks0 nf2 | prefetch B3; stages 3,4
        byh = BRD(0, 3, 0); byl = BRD(1, 3, 0);
        if (stg) { STAGE(NB, 3, kn); STAGE(NB, 4, kn); }
        SB0;
        CL6(2, a0h, a0l, a1h, a1l, bxh, bxl)
        RBAR;
        // ks0 nf3 | prefetch B4
        bxh = BRD(0, 4, 0); bxl = BRD(1, 4, 0);
        SB0;
        CL6(3, a0h, a0l, a1h, a1l, byh, byl)
        RBAR;
        // ks0 nf4 | prefetch A(ks1)+B0(ks1); stages 5,6
        c0h = ARD(0, 0, 1); c0l = ARD(1, 0, 1);
        c1h = ARD(0, 1, 1); c1l = ARD(1, 1, 1);
        byh = BRD(0, 0, 1); byl = BRD(1, 0, 1);
        if (stg) { STAGE(NB, 5, kn); STAGE(NB, 6, kn); }
        SB0;
        CL6(4, a0h, a0l, a1h, a1l, bxh, bxl)
        RBAR;
        // ks1 nf0 | prefetch B1(ks1)
        bxh = BRD(0, 1, 1); bxl = BRD(1, 1, 1);
        SB0;
        CL6(0, c0h, c0l, c1h, c1l, byh, byl)
        RBAR;
        // ks1 nf1 | prefetch B2; stages 7,8
        byh = BRD(0, 2, 1); byl = BRD(1, 2, 1);
        if (stg) { STAGE(NB, 7, kn); STAGE(NB, 8, kn); }
        SB0;
        CL6(1, c0h, c0l, c1h, c1l, bxh, bxl)
        RBAR;
        // ks1 nf2 | prefetch B3
        bxh = BRD(0, 3, 1); bxl = BRD(1, 3, 1);
        SB0;
        CL6(2, c0h, c0l, c1h, c1l, byh, byl)
        RBAR;
        // ks1 nf3 | prefetch B4
        byh = BRD(0, 4, 1); byl = BRD(1, 4, 1);
        SB0;
        CL6(3, c0h, c0l, c1h, c1l, bxh, bxl)
        RBAR;
        // ks1 nf4 | no prefetch (next tile gated by __syncthreads)
        CL6(4, c0h, c0l, c1h, c1l, byh, byl)

        // tile boundary: vmcnt(0)+lgkmcnt(0) drain (stages resident) + swap gate
        __syncthreads();
        char* tmp = CB; CB = NB; NB = tmp;
    }

    #pragma unroll
    for (int mf = 0; mf < 2; ++mf)
        #pragma unroll
        for (int nf = 0; nf < 5; ++nf) {
            int n = n0 + wn + nf * 32 + r32;
            size_t rowb = (size_t)n * MG + m0 + wm + mf * 32 + 4 * hi2;
            #pragma unroll
            for (int g = 0; g < 4; ++g) {
                f32x4 v = { acc[mf][nf][g * 4 + 0], acc[mf][nf][g * 4 + 1],
                            acc[mf][nf][g * 4 + 2], acc[mf][nf][g * 4 + 3] };
                *(f32x4*)(Yt + rowb + 8 * g) = v;
            }
        }
    #undef STAGE
    #undef ARD
    #undef BRD
    #undef TRIP
    #undef RBAR
    #undef SB0
    #undef CL6
}

// ---------------- gather taps -> hm + GN partial sums (R7-proven) ---------------
__global__ __launch_bounds__(256) void k_gather(const float* __restrict__ Yt,
                                                const int* __restrict__ qidx,
                                                const int* __restrict__ apix,
                                                float* __restrict__ hm,
                                                double* __restrict__ part) {
    __shared__ double red1[256 * 4], red2[256 * 4];
    int tid = threadIdx.x;
    int wave = tid >> 6, lane = tid & 63;
    double a1[3] = {0, 0, 0}, a2[3] = {0, 0, 0};
    int gs[3];
    #pragma unroll
    for (int s = 0; s < 3; ++s) gs[s] = (64 * s + lane) / 48;

    for (int it = 0; it < 8; ++it) {
        int p = blockIdx.x * 32 + wave * 8 + it;
        if (!apix[p]) continue;
        int y = p >> 7, x = p & 127;
        float4 hv[3] = {};
        #pragma unroll
        for (int tap = 0; tap < 9; ++tap) {
            int i = y + tap / 3 - 1, j = x + tap % 3 - 1;
            if ((unsigned)i < 128u && (unsigned)j < 128u) {
                int q = qidx[i * NPIX + j];
                if (q >= 0) {
                    const float* yr = Yt + (size_t)q * MG + tap * 768 + lane * 4;
                    #pragma unroll
                    for (int s = 0; s < 3; ++s) {
                        float4 v = *(const float4*)(yr + s * 256);
                        hv[s].x += v.x; hv[s].y += v.y; hv[s].z += v.z; hv[s].w += v.w;
                    }
                }
            }
        }
        int qp = qidx[p];
        if (qp >= 0) {
            #pragma unroll
            for (int s = 0; s < 3; ++s)
                *(float4*)(hm + (size_t)qp * KD + s * 256 + lane * 4) = hv[s];
        }
        #pragma unroll
        for (int s = 0; s < 3; ++s) {
            a1[s] += (double)hv[s].x + (double)hv[s].y + (double)hv[s].z + (double)hv[s].w;
            a2[s] += (double)hv[s].x * hv[s].x + (double)hv[s].y * hv[s].y +
                     (double)hv[s].z * hv[s].z + (double)hv[s].w * hv[s].w;
        }
    }
    #pragma unroll
    for (int g = 0; g < 4; ++g) { red1[tid * 4 + g] = 0.0; red2[tid * 4 + g] = 0.0; }
    #pragma unroll
    for (int s = 0; s < 3; ++s) { red1[tid * 4 + gs[s]] = a1[s]; red2[tid * 4 + gs[s]] = a2[s]; }
    __syncthreads();
    if (tid < 8) {
        int g = tid & 3;
        double s = 0.0;
        if (tid < 4) { for (int i = 0; i < 256; ++i) s += red1[i * 4 + g]; }
        else         { for (int i = 0; i < 256; ++i) s += red2[i * 4 + g]; }
        atomicAdd(&part[tid], s);
    }
}

// ================= k_scorenms (R10-proven: relaxed-poll single consumer) =======
#define SNMS_LDS 44544

__global__ __launch_bounds__(256) void k_scorenms(const float* __restrict__ hm,
                                                  const double* __restrict__ part,
                                                  const float* __restrict__ gamma,
                                                  const float* __restrict__ beta,
                                                  const float* __restrict__ w2,
                                                  const float* __restrict__ b2,
                                                  float* __restrict__ scores,
                                                  const int* __restrict__ qi,
                                                  const int* __restrict__ qj,
                                                  const int* __restrict__ durp,
                                                  int* __restrict__ bar,
                                                  float* __restrict__ out) {
    extern __shared__ char smf[];
    int tid = threadIdx.x;
    int bid = (int)blockIdx.x;
    int lane = tid & 63;

    {
        float mu[4], rs[4];
        const double cnt = 192.0 * 16384.0;
        #pragma unroll
        for (int g = 0; g < 4; ++g) {
            double m = part[g] / cnt;
            double v = part[4 + g] / cnt - m * m;
            mu[g] = (float)m;
            rs[g] = (float)(1.0 / sqrt(v + 1e-5));
        }
        int q = bid * 4 + (tid >> 6);
        const float* hp = hm + (size_t)q * KD;
        float s = 0.f;
        for (int c = lane; c < KD; c += 64) {
            int g = c / 192;
            float v = (hp[c] - mu[g]) * rs[g] * gamma[c] + beta[c];
            s += fmaxf(v, 0.f) * w2[c];
        }
        for (int o = 32; o; o >>= 1) s += __shfl_down(s, o, 64);
        if (lane == 0) scores[q] = 1.f / (1.f + expf(-(s + b2[0])));
    }
    __syncthreads();
    if (tid == 0)
        __hip_atomic_fetch_add(&bar[2], 1, __ATOMIC_RELEASE, __HIP_MEMORY_SCOPE_AGENT);
    if (bid != 0) return;

    if (tid == 0) {
        while (__hip_atomic_load(&bar[2], __ATOMIC_RELAXED, __HIP_MEMORY_SCOPE_AGENT) < 637)
            __builtin_amdgcn_s_sleep(8);
        (void)__hip_atomic_load(&bar[2], __ATOMIC_ACQUIRE, __HIP_MEMORY_SCOPE_AGENT);
    }
    __syncthreads();

    {
        unsigned long long* key = (unsigned long long*)smf;
        float* ss = (float*)(smf + 20384);
        float* ee = (float*)(smf + 30576);
        unsigned char* st = (unsigned char*)(smf + 40768);
        unsigned long long* wm0 = (unsigned long long*)(smf + 43328);
        unsigned long long* wm1 = (unsigned long long*)(smf + 43360);
        __shared__ int sh_keeper, keepq[5];
        __shared__ float sh_s0, sh_e0;

        float delta = (float)(*durp) / 128.f;
        for (int i = tid; i < MASKM; i += 256) {
            unsigned sb = __float_as_uint(scores[i]);
            key[i] = ((unsigned long long)sb << 32) | (unsigned)(4095 - i);
            ss[i] = qi[i] * delta;
            ee[i] = (qj[i] + 1) * delta;
            st[i] = 0;
        }
        __syncthreads();
        for (int round = 0; round < 5; ++round) {
            unsigned long long b0 = 0, b1 = 0;
            for (int i = tid; i < MASKM; i += 256) {
                unsigned char s = st[i];
                unsigned long long k = key[i];
                if (s == 0) { if (k > b0) b0 = k; }
                else if (s == 1) { if (k > b1) b1 = k; }
            }
            for (int o = 32; o; o >>= 1) {
                unsigned lo0 = __shfl_down((unsigned)b0, o, 64);
                unsigned hi0 = __shfl_down((unsigned)(b0 >> 32), o, 64);
                unsigned long long u0 = ((unsigned long long)hi0 << 32) | lo0;
                unsigned lo1 = __shfl_down((unsigned)b1, o, 64);
                unsigned hi1 = __shfl_down((unsigned)(b1 >> 32), o, 64);
                unsigned long long u1 = ((unsigned long long)hi1 << 32) | lo1;
                if (u0 > b0) b0 = u0;
                if (u1 > b1) b1 = u1;
            }
            if ((tid & 63) == 0) { wm0[tid >> 6] = b0; wm1[tid >> 6] = b1; }
            __syncthreads();
            if (tid == 0) {
                unsigned long long B0 = 0, B1 = 0;
                for (int w = 0; w < 4; ++w) {
                    if (wm0[w] > B0) B0 = wm0[w];
                    if (wm1[w] > B1) B1 = wm1[w];
                }
                int keeper = (B0 != 0);
                unsigned long long B = keeper ? B0 : B1;
                int q = 4095 - (int)(B & 0xFFFFFFFFull);
                st[q] = keeper ? 2 : 3;
                sh_keeper = keeper;
                sh_s0 = ss[q]; sh_e0 = ee[q];
                keepq[round] = q;
            }
            __syncthreads();
            if (sh_keeper) {
                float s0 = sh_s0, e0 = sh_e0;
                for (int i = tid; i < MASKM; i += 256) {
                    if (st[i] == 0) {
                        float inter = fminf(ee[i], e0) - fmaxf(ss[i], s0);
                        if (inter > 0.f) {
                            float uni = fmaxf(ee[i], e0) - fminf(ss[i], s0);
                            if (inter / uni > 0.5f) st[i] = 1;
                        }
                    }
                }
            }
            __syncthreads();
        }
        if (tid < 5) { out[tid * 2] = ss[keepq[tid]]; out[tid * 2 + 1] = ee[keepq[tid]]; }
    }
}

// ---------------- launch ----------------
extern "C" void kernel_launch(void* const* d_in, const int* in_sizes, int n_in,
                              void* d_out, int out_size, void* d_ws, size_t ws_size,
                              hipStream_t stream) {
    const float* fea   = (const float*)d_in[0];
    const int*   dur   = (const int*)d_in[1];
    const float* w1    = (const float*)d_in[2];
    const float* gamma = (const float*)d_in[3];
    const float* beta  = (const float*)d_in[4];
    const float* w2    = (const float*)d_in[5];
    const float* b2    = (const float*)d_in[6];
    float* out = (float*)d_out;

    char* ws = (char*)d_ws;
    int*    qi     = (int*)(ws + OFF_QI);
    int*    qj     = (int*)(ws + OFF_QJ);
    int*    qidx   = (int*)(ws + OFF_QIDX);
    int*    apix   = (int*)(ws + OFF_APIX);
    int*    bar    = (int*)(ws + OFF_BAR);
    double* part   = (double*)(ws + OFF_PART);
    float*  scores = (float*)(ws + OFF_SC);
    float*  hm     = (float*)(ws + OFF_HM);
    unsigned short* AhU = (unsigned short*)(ws + OFF_AH);
    unsigned short* AlU = (unsigned short*)(ws + OFF_AL);
    unsigned short* BhU = (unsigned short*)(ws + OFF_BH);
    unsigned short* BlU = (unsigned short*)(ws + OFF_BL);
    float*  Yt     = (float*)(ws + OFF_YT);

    static bool attr_set = false;
    if (!attr_set) {
        hipFuncSetAttribute((const void*)k_prep,
                            hipFuncAttributeMaxDynamicSharedMemorySize, PREP_LDS);
        hipFuncSetAttribute((const void*)k_gemm,
                            hipFuncAttributeMaxDynamicSharedMemorySize, 2 * BUFSZ);
        hipFuncSetAttribute((const void*)k_scorenms,
                            hipFuncAttributeMaxDynamicSharedMemorySize, SNMS_LDS);
        attr_set = true;
    }

    k_prep<<<256, 256, PREP_LDS, stream>>>(fea, w1, qi, qj, qidx, apix, part, bar,
                                           AhU, AlU, BhU, BlU);
    k_gemm<<<216, 512, 2 * BUFSZ, stream>>>(AhU, AlU, BhU, BlU, Yt);
    k_gather<<<512, 256, 0, stream>>>(Yt, qidx, apix, hm, part);
    k_scorenms<<<637, 256, SNMS_LDS, stream>>>(hm, part, gamma, beta, w2, b2,
                                               scores, qi, qj, dur, bar, out);
}

// Round 13
// 242.651 us; speedup vs baseline: 2.6336x; 1.0727x over previous
//
#include <hip/hip_runtime.h>
#include <math.h>

// ---------------- problem constants ----------------
#define NPIX 128
#define MASKM 2548
#define NPAD 2560          // padded q count (20*128)
#define MG   6912          // GEMM M = 9 taps * 768
#define KD   768

typedef __attribute__((ext_vector_type(8))) short bf16x8;
typedef __attribute__((ext_vector_type(4))) float f32x4;
typedef __attribute__((ext_vector_type(16))) float f32x16;
typedef __attribute__((ext_vector_type(8))) unsigned short ushort8;

// ---------------- workspace layout ----------------
static constexpr size_t OFF_QI   = 0;
static constexpr size_t OFF_QJ   = OFF_QI + NPAD * 4;
static constexpr size_t OFF_QIDX = OFF_QJ + NPAD * 4;
static constexpr size_t OFF_APIX = OFF_QIDX + 16384 * 4;
static constexpr size_t OFF_BAR  = OFF_APIX + 16384 * 4;   // 4 ints (sync counters)
static constexpr size_t OFF_PART = OFF_BAR + 128 * 4;
static constexpr size_t OFF_SC   = OFF_PART + 512 * 8 * 8;
static constexpr size_t OFF_HM   = OFF_SC + NPAD * 4;
static constexpr size_t OFF_AH   = OFF_HM + (size_t)MASKM * KD * 4;
static constexpr size_t OFF_AL   = OFF_AH + (size_t)MG * KD * 2;
static constexpr size_t OFF_BH   = OFF_AL + (size_t)MG * KD * 2;
static constexpr size_t OFF_BL   = OFF_BH + (size_t)NPAD * KD * 2;
static constexpr size_t OFF_YT   = OFF_BL + (size_t)NPAD * KD * 2;

// ---------------- bf16 hi/lo split helpers ----------------
__device__ __forceinline__ unsigned short f2bf(float f) {
    unsigned u = __float_as_uint(f);
    u = u + 0x7FFFu + ((u >> 16) & 1u);       // RNE
    return (unsigned short)(u >> 16);
}
__device__ __forceinline__ float bf2f(unsigned short h) {
    return __uint_as_float(((unsigned)h) << 16);
}

// ---------------- mask structure (closed form) ----------------
__device__ __forceinline__ bool mask_allowed(int i, int d) {
    if (d == 0) return true;
    if (d <= 15) return true;
    if (d <= 31) return (d >= 17) && ((d & 1) == 1) && ((i & 1) == 0);
    if (d <= 63) return (d >= 35) && ((d & 3) == 3) && ((i & 3) == 0);
    return (d >= 71) && ((d & 7) == 7) && ((i & 7) == 0);
}
__device__ __forceinline__ bool masked_ij(int i, int j) {
    return (j >= i) && (j < NPIX) && (i >= 0) && mask_allowed(i, j - i);
}

// closed-form inverse: rank r within row i -> offset d.
__device__ __forceinline__ int rank_to_d(int i, int r) {
    int rem = NPIX - i;
    int c1 = rem < 16 ? rem : 16;
    if (r < c1) return r;
    r -= c1;
    int h2 = (rem - 1) < 31 ? (rem - 1) : 31;
    int c2 = (((i & 1) == 0) && h2 >= 17) ? ((h2 - 17) >> 1) + 1 : 0;
    if (r < c2) return 17 + 2 * r;
    r -= c2;
    int h3 = (rem - 1) < 63 ? (rem - 1) : 63;
    int c3 = (((i & 3) == 0) && h3 >= 35) ? ((h3 - 35) >> 2) + 1 : 0;
    if (r < c3) return 35 + 4 * r;
    r -= c3;
    return 71 + 8 * r;
}

// ======== k_prep: fill(64) | buildB(96 x 8ch) | prepA(288 x 2s) = 448 blocks ===
// R13: split for occupancy. R12 had 256 blocks = 1/CU with long serial bodies;
// now 448 blocks, 37.9KB LDS -> ~4 blocks/CU capacity, ~2x TLP, same work.
#define PREP_LDS 37888     // max(prepA tile 64*148*4, buildB tab 32KB+cnt+startv)
#define PASTR 148

__global__ __launch_bounds__(256) void k_prep(const float* __restrict__ fea,
                                              const float* __restrict__ w1,
                                              int* __restrict__ qi, int* __restrict__ qj,
                                              int* __restrict__ qidx, int* __restrict__ apix,
                                              double* __restrict__ part, int* __restrict__ bar,
                                              unsigned short* __restrict__ Ah,
                                              unsigned short* __restrict__ Al,
                                              unsigned short* __restrict__ Bh,
                                              unsigned short* __restrict__ Bl) {
    extern __shared__ char smp[];
    int tid = threadIdx.x;
    int bid = blockIdx.x;

    if (bid < 64) {
        // ---------------- FILL ----------------
        int* cnt = (int*)smp;
        int* startv = cnt + NPIX;
        if (tid < NPIX) {
            int c = 0;
            for (int d = 0; tid + d < NPIX; ++d) if (mask_allowed(tid, d)) ++c;
            cnt[tid] = c;
        }
        __syncthreads();
        if (tid == 0) {
            int s = 0;
            for (int r = 0; r < NPIX; ++r) { startv[r] = s; s += cnt[r]; }
        }
        __syncthreads();
        int p = bid * 256 + tid;
        int i = p >> 7, j = p & 127;
        int q = -1;
        if (masked_ij(i, j)) {
            int d = j - i, r = 0;
            for (int dd = 0; dd < d; ++dd) r += mask_allowed(i, dd) ? 1 : 0;
            q = startv[i] + r;
            qi[q] = i; qj[q] = j;
        }
        qidx[p] = q;
        int act = 0;
        #pragma unroll
        for (int dy = -1; dy <= 1; ++dy)
            #pragma unroll
            for (int dx = -1; dx <= 1; ++dx)
                if (masked_ij(i + dy, j + dx)) act = 1;
        apix[p] = act;
        if (bid == 0) {
            if (tid < 8) part[tid] = 0.0;
            if (tid >= 8 && tid < 12) bar[tid - 8] = 0;
        }
    } else if (bid < 160) {
        // ---------------- BUILD B (8 channels / block, 96 blocks) ----------------
        float* tab = (float*)smp;                       // [c 8][lvl 8][x 128] = 32KB
        int* cnt = (int*)(smp + 32768);
        int* startv = (int*)(smp + 33280);              // 129 ints
        int cb = bid - 64, c0 = cb * 8;
        if (tid < NPIX) {
            int c = 0;
            for (int d = 0; tid + d < NPIX; ++d) if (mask_allowed(tid, d)) ++c;
            cnt[tid] = c;
        }
        __syncthreads();
        if (tid == 0) {
            int s = 0;
            for (int r = 0; r < NPIX; ++r) { startv[r] = s; s += cnt[r]; }
            startv[NPIX] = s;
        }
        for (int idx = tid; idx < 8 * NPIX; idx += 256) {
            int c = idx >> 7, x = idx & 127;
            tab[(c * 8) * 128 + x] = fea[(size_t)(c0 + c) * NPIX + x];
        }
        __syncthreads();
        for (int lvl = 1; lvl < 8; ++lvl) {
            int half = 1 << (lvl - 1), full = 1 << lvl;
            for (int idx = tid; idx < 8 * NPIX; idx += 256) {
                int c = idx >> 7, x = idx & 127;
                if (x + full <= NPIX)
                    tab[(c * 8 + lvl) * 128 + x] =
                        fmaxf(tab[(c * 8 + lvl - 1) * 128 + x],
                              tab[(c * 8 + lvl - 1) * 128 + x + half]);
            }
            __syncthreads();
        }
        for (int q = tid; q < NPAD; q += 256) {
            ushort8 vh = {}, vl = {};
            if (q < MASKM) {
                int i = 0;
                #pragma unroll
                for (int s = 64; s >= 1; s >>= 1) {
                    int cand = i + s;
                    if (cand <= 127 && startv[cand] <= q) i = cand;
                }
                int d = rank_to_d(i, q - startv[i]);
                int j = i + d;
                int len = d + 1;
                int lvl = 31 - __clz(len);
                int x2 = j + 1 - (1 << lvl);
                #pragma unroll
                for (int c = 0; c < 8; ++c) {
                    float v = fmaxf(tab[(c * 8 + lvl) * 128 + i], tab[(c * 8 + lvl) * 128 + x2]);
                    unsigned short hh = f2bf(v);
                    vh[c] = hh; vl[c] = f2bf(v - bf2f(hh));
                }
            }
            *(ushort8*)(Bh + (size_t)q * KD + c0) = vh;
            *(ushort8*)(Bl + (size_t)q * KD + c0) = vl;
        }
    } else {
        // ---------------- PREP A (288 blocks, 2 s-iterations each) ----------------
        float* tile = (float*)smp;
        int pb = bid - 160;                             // 0..287
        int co0 = (pb % 12) * 64, ci0 = ((pb / 12) % 12) * 64;
        int sh = pb / 144;                              // 0 or 1
        for (int s = sh * 2; s < sh * 2 + 2; ++s) {
            int cib = ci0 + s * 16;
            __syncthreads();
            for (int idx = tid; idx < 2304; idx += 256) {
                int row = idx / 36, c4 = idx % 36;
                float4 v = *(const float4*)(w1 + (size_t)(co0 + row) * MG + cib * 9 + c4 * 4);
                *(float4*)&tile[row * PASTR + c4 * 4] = v;
            }
            __syncthreads();
            for (int idx = tid; idx < 1152; idx += 256) {
                int tap = idx / 128;
                int rem = idx - tap * 128;
                int co = rem >> 1, half = rem & 1;
                ushort8 vh, vl;
                #pragma unroll
                for (int c = 0; c < 8; ++c) {
                    float v = tile[co * PASTR + (half * 8 + c) * 9 + tap];
                    unsigned short hi = f2bf(v);
                    vh[c] = hi;
                    vl[c] = f2bf(v - bf2f(hi));
                }
                size_t ob = (size_t)(tap * 768 + co0 + co) * KD + cib + half * 8;
                *(ushort8*)(Ah + ob) = vh;
                *(ushort8*)(Al + ob) = vl;
            }
        }
    }
}

// ---------------- bf16x3 MFMA GEMM (R12, FROZEN: 86.8us best measured) ----------
#define BUFSZ   73728      // Ah(16K) | Al(16K) | Bh(20K) | Bl(20K)
#define SB_BH   32768

__global__ __launch_bounds__(512, 1) void k_gemm(const unsigned short* __restrict__ Ah,
                                                 const unsigned short* __restrict__ Al,
                                                 const unsigned short* __restrict__ Bh,
                                                 const unsigned short* __restrict__ Bl,
                                                 float* __restrict__ Yt) {
    extern __shared__ char sm[];               // 2 * BUFSZ = 144 KB dynamic LDS
    int tid = threadIdx.x;
    int wave = tid >> 6, lane = tid & 63;

    int bid = (int)blockIdx.x;
    int xcd = bid & 7, loc = bid >> 3;         // 8 XCDs x 27 M-tiles
    int m0 = loc * 256, n0 = xcd * 320;

    int wm = (wave & 3) << 6, wn = (wave >> 2) * 160;
    int r32 = lane & 31, hi2 = lane >> 5;
    int rb  = (r32 >> 4) * 1024 + hi2 * 256 + (r32 & 15) * 16;
    int awb = (wm >> 4) * 1024 + rb;
    int bwb = (wn >> 4) * 1024 + rb;

    int lrow = lane & 15, lchk = lane >> 4;
    const unsigned short* sp[9];
    int so[9];
    #pragma unroll
    for (int s = 0; s < 9; ++s) {
        int gid = wave * 9 + s;
        const unsigned short* base;
        int row0, ldso;
        if (gid < 16)      { base = Ah; row0 = m0 + gid * 16;        ldso = gid * 1024; }
        else if (gid < 32) { base = Al; row0 = m0 + (gid - 16) * 16; ldso = 16384 + (gid - 16) * 1024; }
        else if (gid < 52) { base = Bh; row0 = n0 + (gid - 32) * 16; ldso = SB_BH + (gid - 32) * 1024; }
        else               { base = Bl; row0 = n0 + (gid - 52) * 16; ldso = SB_BH + 20480 + (gid - 52) * 1024; }
        sp[s] = base + (size_t)(row0 + lrow) * KD + lchk * 8;
        so[s] = ldso;
    }

    f32x16 acc[2][5] = {};
    char* CB = sm;
    char* NB = sm + BUFSZ;

    #define STAGE(DST, s, koff) __builtin_amdgcn_global_load_lds( \
        (const __attribute__((address_space(1))) unsigned int*)(sp[s] + (koff)), \
        (__attribute__((address_space(3))) unsigned int*)((DST) + so[s]), 16, 0, 0)
    #define ARD(hl, mf, ks) (*(const bf16x8*)(CB + (hl) * 16384 + awb + (mf) * 2048 + (ks) * 512))
    #define BRD(hl, nf, ks) (*(const bf16x8*)(CB + SB_BH + (hl) * 20480 + bwb + (nf) * 2048 + (ks) * 512))
    #define TRIP(mf, nf, xh, xl, yh, yl) \
        acc[mf][nf] = __builtin_amdgcn_mfma_f32_32x32x16_bf16(xh, yh, acc[mf][nf], 0, 0, 0); \
        acc[mf][nf] = __builtin_amdgcn_mfma_f32_32x32x16_bf16(xh, yl, acc[mf][nf], 0, 0, 0); \
        acc[mf][nf] = __builtin_amdgcn_mfma_f32_32x32x16_bf16(xl, yh, acc[mf][nf], 0, 0, 0);
    #define RBAR __builtin_amdgcn_s_barrier()
    #define SB0  __builtin_amdgcn_sched_barrier(0)
    #define CL6(nf, xh0, xl0, xh1, xl1, yh, yl) \
        __builtin_amdgcn_s_setprio(1); \
        TRIP(0, nf, xh0, xl0, yh, yl) \
        TRIP(1, nf, xh1, xl1, yh, yl) \
        __builtin_amdgcn_s_setprio(0);

    #pragma unroll
    for (int s = 0; s < 9; ++s) STAGE(CB, s, 0);
    __syncthreads();

    for (int t = 0; t < 24; ++t) {
        int kn = (t + 1) * 32;
        bool stg = (t < 23);
        bf16x8 a0h, a0l, a1h, a1l;
        bf16x8 c0h, c0l, c1h, c1l;
        bf16x8 bxh, bxl, byh, byl;

        a0h = ARD(0, 0, 0); a0l = ARD(1, 0, 0);
        a1h = ARD(0, 1, 0); a1l = ARD(1, 1, 0);
        bxh = BRD(0, 0, 0); bxl = BRD(1, 0, 0);
        if (stg) { STAGE(NB, 0, kn); STAGE(NB, 1, kn); STAGE(NB, 2, kn); }
        RBAR;

        byh = BRD(0, 1, 0); byl = BRD(1, 1, 0);
        SB0;
        CL6(0, a0h, a0l, a1h, a1l, bxh, bxl)
        RBAR;
        bxh = BRD(0, 2, 0); bxl = BRD(1, 2, 0);
        SB0;
        CL6(1, a0h, a0l, a1h, a1l, byh, byl)
        RBAR;
        byh = BRD(0, 3, 0); byl = BRD(1, 3, 0);
        if (stg) { STAGE(NB, 3, kn); STAGE(NB, 4, kn); }
        SB0;
        CL6(2, a0h, a0l, a1h, a1l, bxh, bxl)
        RBAR;
        bxh = BRD(0, 4, 0); bxl = BRD(1, 4, 0);
        SB0;
        CL6(3, a0h, a0l, a1h, a1l, byh, byl)
        RBAR;
        c0h = ARD(0, 0, 1); c0l = ARD(1, 0, 1);
        c1h = ARD(0, 1, 1); c1l = ARD(1, 1, 1);
        byh = BRD(0, 0, 1); byl = BRD(1, 0, 1);
        if (stg) { STAGE(NB, 5, kn); STAGE(NB, 6, kn); }
        SB0;
        CL6(4, a0h, a0l, a1h, a1l, bxh, bxl)
        RBAR;
        bxh = BRD(0, 1, 1); bxl = BRD(1, 1, 1);
        SB0;
        CL6(0, c0h, c0l, c1h, c1l, byh, byl)
        RBAR;
        byh = BRD(0, 2, 1); byl = BRD(1, 2, 1);
        if (stg) { STAGE(NB, 7, kn); STAGE(NB, 8, kn); }
        SB0;
        CL6(1, c0h, c0l, c1h, c1l, bxh, bxl)
        RBAR;
        bxh = BRD(0, 3, 1); bxl = BRD(1, 3, 1);
        SB0;
        CL6(2, c0h, c0l, c1h, c1l, byh, byl)
        RBAR;
        byh = BRD(0, 4, 1); byl = BRD(1, 4, 1);
        SB0;
        CL6(3, c0h, c0l, c1h, c1l, bxh, bxl)
        RBAR;
        CL6(4, c0h, c0l, c1h, c1l, byh, byl)

        __syncthreads();
        char* tmp = CB; CB = NB; NB = tmp;
    }

    #pragma unroll
    for (int mf = 0; mf < 2; ++mf)
        #pragma unroll
        for (int nf = 0; nf < 5; ++nf) {
            int n = n0 + wn + nf * 32 + r32;
            size_t rowb = (size_t)n * MG + m0 + wm + mf * 32 + 4 * hi2;
            #pragma unroll
            for (int g = 0; g < 4; ++g) {
                f32x4 v = { acc[mf][nf][g * 4 + 0], acc[mf][nf][g * 4 + 1],
                            acc[mf][nf][g * 4 + 2], acc[mf][nf][g * 4 + 3] };
                *(f32x4*)(Yt + rowb + 8 * g) = v;
            }
        }
    #undef STAGE
    #undef ARD
    #undef BRD
    #undef TRIP
    #undef RBAR
    #undef SB0
    #undef CL6
}

// ---------------- gather taps -> hm + GN partial sums --------------------------
// R13: grid 512 -> 1024 blocks, 4 pixels/wave (was 8). Traffic ~50MB (= ~8us at
// BW) but measured tier suggests latency-bound at 2 waves/SIMD; 4 waves/SIMD
// doubles latency hiding. Per-pixel arithmetic order unchanged (absmax-safe).
__global__ __launch_bounds__(256) void k_gather(const float* __restrict__ Yt,
                                                const int* __restrict__ qidx,
                                                const int* __restrict__ apix,
                                                float* __restrict__ hm,
                                                double* __restrict__ part) {
    __shared__ double red1[256 * 4], red2[256 * 4];
    int tid = threadIdx.x;
    int wave = tid >> 6, lane = tid & 63;
    double a1[3] = {0, 0, 0}, a2[3] = {0, 0, 0};
    int gs[3];
    #pragma unroll
    for (int s = 0; s < 3; ++s) gs[s] = (64 * s + lane) / 48;

    for (int it = 0; it < 4; ++it) {
        int p = blockIdx.x * 16 + wave * 4 + it;   // wave-uniform pixel
        if (!apix[p]) continue;
        int y = p >> 7, x = p & 127;
        float4 hv[3] = {};
        #pragma unroll
        for (int tap = 0; tap < 9; ++tap) {
            int i = y + tap / 3 - 1, j = x + tap % 3 - 1;
            if ((unsigned)i < 128u && (unsigned)j < 128u) {
                int q = qidx[i * NPIX + j];
                if (q >= 0) {
                    const float* yr = Yt + (size_t)q * MG + tap * 768 + lane * 4;
                    #pragma unroll
                    for (int s = 0; s < 3; ++s) {
                        float4 v = *(const float4*)(yr + s * 256);
                        hv[s].x += v.x; hv[s].y += v.y; hv[s].z += v.z; hv[s].w += v.w;
                    }
                }
            }
        }
        int qp = qidx[p];
        if (qp >= 0) {
            #pragma unroll
            for (int s = 0; s < 3; ++s)
                *(float4*)(hm + (size_t)qp * KD + s * 256 + lane * 4) = hv[s];
        }
        #pragma unroll
        for (int s = 0; s < 3; ++s) {
            a1[s] += (double)hv[s].x + (double)hv[s].y + (double)hv[s].z + (double)hv[s].w;
            a2[s] += (double)hv[s].x * hv[s].x + (double)hv[s].y * hv[s].y +
                     (double)hv[s].z * hv[s].z + (double)hv[s].w * hv[s].w;
        }
    }
    #pragma unroll
    for (int g = 0; g < 4; ++g) { red1[tid * 4 + g] = 0.0; red2[tid * 4 + g] = 0.0; }
    #pragma unroll
    for (int s = 0; s < 3; ++s) { red1[tid * 4 + gs[s]] = a1[s]; red2[tid * 4 + gs[s]] = a2[s]; }
    __syncthreads();
    if (tid < 8) {
        int g = tid & 3;
        double s = 0.0;
        if (tid < 4) { for (int i = 0; i < 256; ++i) s += red1[i * 4 + g]; }
        else         { for (int i = 0; i < 256; ++i) s += red2[i * 4 + g]; }
        atomicAdd(&part[tid], s);
    }
}

// ================= k_scorenms (R10-proven: relaxed-poll single consumer) =======
#define SNMS_LDS 44544

__global__ __launch_bounds__(256) void k_scorenms(const float* __restrict__ hm,
                                                  const double* __restrict__ part,
                                                  const float* __restrict__ gamma,
                                                  const float* __restrict__ beta,
                                                  const float* __restrict__ w2,
                                                  const float* __restrict__ b2,
                                                  float* __restrict__ scores,
                                                  const int* __restrict__ qi,
                                                  const int* __restrict__ qj,
                                                  const int* __restrict__ durp,
                                                  int* __restrict__ bar,
                                                  float* __restrict__ out) {
    extern __shared__ char smf[];
    int tid = threadIdx.x;
    int bid = (int)blockIdx.x;
    int lane = tid & 63;

    {
        float mu[4], rs[4];
        const double cnt = 192.0 * 16384.0;
        #pragma unroll
        for (int g = 0; g < 4; ++g) {
            double m = part[g] / cnt;
            double v = part[4 + g] / cnt - m * m;
            mu[g] = (float)m;
            rs[g] = (float)(1.0 / sqrt(v + 1e-5));
        }
        int q = bid * 4 + (tid >> 6);
        const float* hp = hm + (size_t)q * KD;
        float s = 0.f;
        for (int c = lane; c < KD; c += 64) {
            int g = c / 192;
            float v = (hp[c] - mu[g]) * rs[g] * gamma[c] + beta[c];
            s += fmaxf(v, 0.f) * w2[c];
        }
        for (int o = 32; o; o >>= 1) s += __shfl_down(s, o, 64);
        if (lane == 0) scores[q] = 1.f / (1.f + expf(-(s + b2[0])));
    }
    __syncthreads();
    if (tid == 0)
        __hip_atomic_fetch_add(&bar[2], 1, __ATOMIC_RELEASE, __HIP_MEMORY_SCOPE_AGENT);
    if (bid != 0) return;

    if (tid == 0) {
        while (__hip_atomic_load(&bar[2], __ATOMIC_RELAXED, __HIP_MEMORY_SCOPE_AGENT) < 637)
            __builtin_amdgcn_s_sleep(8);
        (void)__hip_atomic_load(&bar[2], __ATOMIC_ACQUIRE, __HIP_MEMORY_SCOPE_AGENT);
    }
    __syncthreads();

    {
        unsigned long long* key = (unsigned long long*)smf;
        float* ss = (float*)(smf + 20384);
        float* ee = (float*)(smf + 30576);
        unsigned char* st = (unsigned char*)(smf + 40768);
        unsigned long long* wm0 = (unsigned long long*)(smf + 43328);
        unsigned long long* wm1 = (unsigned long long*)(smf + 43360);
        __shared__ int sh_keeper, keepq[5];
        __shared__ float sh_s0, sh_e0;

        float delta = (float)(*durp) / 128.f;
        for (int i = tid; i < MASKM; i += 256) {
            unsigned sb = __float_as_uint(scores[i]);
            key[i] = ((unsigned long long)sb << 32) | (unsigned)(4095 - i);
            ss[i] = qi[i] * delta;
            ee[i] = (qj[i] + 1) * delta;
            st[i] = 0;
        }
        __syncthreads();
        for (int round = 0; round < 5; ++round) {
            unsigned long long b0 = 0, b1 = 0;
            for (int i = tid; i < MASKM; i += 256) {
                unsigned char s = st[i];
                unsigned long long k = key[i];
                if (s == 0) { if (k > b0) b0 = k; }
                else if (s == 1) { if (k > b1) b1 = k; }
            }
            for (int o = 32; o; o >>= 1) {
                unsigned lo0 = __shfl_down((unsigned)b0, o, 64);
                unsigned hi0 = __shfl_down((unsigned)(b0 >> 32), o, 64);
                unsigned long long u0 = ((unsigned long long)hi0 << 32) | lo0;
                unsigned lo1 = __shfl_down((unsigned)b1, o, 64);
                unsigned hi1 = __shfl_down((unsigned)(b1 >> 32), o, 64);
                unsigned long long u1 = ((unsigned long long)hi1 << 32) | lo1;
                if (u0 > b0) b0 = u0;
                if (u1 > b1) b1 = u1;
            }
            if ((tid & 63) == 0) { wm0[tid >> 6] = b0; wm1[tid >> 6] = b1; }
            __syncthreads();
            if (tid == 0) {
                unsigned long long B0 = 0, B1 = 0;
                for (int w = 0; w < 4; ++w) {
                    if (wm0[w] > B0) B0 = wm0[w];
                    if (wm1[w] > B1) B1 = wm1[w];
                }
                int keeper = (B0 != 0);
                unsigned long long B = keeper ? B0 : B1;
                int q = 4095 - (int)(B & 0xFFFFFFFFull);
                st[q] = keeper ? 2 : 3;
                sh_keeper = keeper;
                sh_s0 = ss[q]; sh_e0 = ee[q];
                keepq[round] = q;
            }
            __syncthreads();
            if (sh_keeper) {
                float s0 = sh_s0, e0 = sh_e0;
                for (int i = tid; i < MASKM; i += 256) {
                    if (st[i] == 0) {
                        float inter = fminf(ee[i], e0) - fmaxf(ss[i], s0);
                        if (inter > 0.f) {
                            float uni = fmaxf(ee[i], e0) - fminf(ss[i], s0);
                            if (inter / uni > 0.5f) st[i] = 1;
                        }
                    }
                }
            }
            __syncthreads();
        }
        if (tid < 5) { out[tid * 2] = ss[keepq[tid]]; out[tid * 2 + 1] = ee[keepq[tid]]; }
    }
}

// ---------------- launch ----------------
extern "C" void kernel_launch(void* const* d_in, const int* in_sizes, int n_in,
                              void* d_out, int out_size, void* d_ws, size_t ws_size,
                              hipStream_t stream) {
    const float* fea   = (const float*)d_in[0];
    const int*   dur   = (const int*)d_in[1];
    const float* w1    = (const float*)d_in[2];
    const float* gamma = (const float*)d_in[3];
    const float* beta  = (const float*)d_in[4];
    const float* w2    = (const float*)d_in[5];
    const float* b2    = (const float*)d_in[6];
    float* out = (float*)d_out;

    char* ws = (char*)d_ws;
    int*    qi     = (int*)(ws + OFF_QI);
    int*    qj     = (int*)(ws + OFF_QJ);
    int*    qidx   = (int*)(ws + OFF_QIDX);
    int*    apix   = (int*)(ws + OFF_APIX);
    int*    bar    = (int*)(ws + OFF_BAR);
    double* part   = (double*)(ws + OFF_PART);
    float*  scores = (float*)(ws + OFF_SC);
    float*  hm     = (float*)(ws + OFF_HM);
    unsigned short* AhU = (unsigned short*)(ws + OFF_AH);
    unsigned short* AlU = (unsigned short*)(ws + OFF_AL);
    unsigned short* BhU = (unsigned short*)(ws + OFF_BH);
    unsigned short* BlU = (unsigned short*)(ws + OFF_BL);
    float*  Yt     = (float*)(ws + OFF_YT);

    static bool attr_set = false;
    if (!attr_set) {
        hipFuncSetAttribute((const void*)k_prep,
                            hipFuncAttributeMaxDynamicSharedMemorySize, PREP_LDS);
        hipFuncSetAttribute((const void*)k_gemm,
                            hipFuncAttributeMaxDynamicSharedMemorySize, 2 * BUFSZ);
        hipFuncSetAttribute((const void*)k_scorenms,
                            hipFuncAttributeMaxDynamicSharedMemorySize, SNMS_LDS);
        attr_set = true;
    }

    k_prep<<<448, 256, PREP_LDS, stream>>>(fea, w1, qi, qj, qidx, apix, part, bar,
                                           AhU, AlU, BhU, BlU);
    k_gemm<<<216, 512, 2 * BUFSZ, stream>>>(AhU, AlU, BhU, BlU, Yt);
    k_gather<<<1024, 256, 0, stream>>>(Yt, qidx, apix, hm, part);
    k_scorenms<<<637, 256, SNMS_LDS, stream>>>(hm, part, gamma, beta, w2, b2,
                                               scores, qi, qj, dur, bar, out);
}

// Round 14
// 240.278 us; speedup vs baseline: 2.6596x; 1.0099x over previous
//
#include <hip/hip_runtime.h>
#include <math.h>

// ---------------- problem constants ----------------
#define NPIX 128
#define MASKM 2548
#define NPAD 2560          // padded q count (20*128)
#define MG   6912          // GEMM M = 9 taps * 768
#define KD   768

typedef __attribute__((ext_vector_type(8))) short bf16x8;
typedef __attribute__((ext_vector_type(4))) float f32x4;
typedef __attribute__((ext_vector_type(16))) float f32x16;
typedef __attribute__((ext_vector_type(8))) unsigned short ushort8;

// ---------------- workspace layout ----------------
static constexpr size_t OFF_QI   = 0;
static constexpr size_t OFF_QJ   = OFF_QI + NPAD * 4;
static constexpr size_t OFF_QIDX = OFF_QJ + NPAD * 4;
static constexpr size_t OFF_APIX = OFF_QIDX + 16384 * 4;
static constexpr size_t OFF_BAR  = OFF_APIX + 16384 * 4;   // 4 ints (sync + list count)
static constexpr size_t OFF_LIST = OFF_BAR + 128 * 4;      // compacted active pixels
static constexpr size_t OFF_PART = OFF_LIST + 16384 * 4;
static constexpr size_t OFF_SC   = OFF_PART + 512 * 8 * 8;
static constexpr size_t OFF_HM   = OFF_SC + NPAD * 4;
static constexpr size_t OFF_AH   = OFF_HM + (size_t)MASKM * KD * 4;
static constexpr size_t OFF_AL   = OFF_AH + (size_t)MG * KD * 2;
static constexpr size_t OFF_BH   = OFF_AL + (size_t)MG * KD * 2;
static constexpr size_t OFF_BL   = OFF_BH + (size_t)NPAD * KD * 2;
static constexpr size_t OFF_YT   = OFF_BL + (size_t)NPAD * KD * 2;

// ---------------- bf16 hi/lo split helpers ----------------
__device__ __forceinline__ unsigned short f2bf(float f) {
    unsigned u = __float_as_uint(f);
    u = u + 0x7FFFu + ((u >> 16) & 1u);       // RNE
    return (unsigned short)(u >> 16);
}
__device__ __forceinline__ float bf2f(unsigned short h) {
    return __uint_as_float(((unsigned)h) << 16);
}

// ---------------- mask structure (closed form) ----------------
__device__ __forceinline__ bool mask_allowed(int i, int d) {
    if (d == 0) return true;
    if (d <= 15) return true;
    if (d <= 31) return (d >= 17) && ((d & 1) == 1) && ((i & 1) == 0);
    if (d <= 63) return (d >= 35) && ((d & 3) == 3) && ((i & 3) == 0);
    return (d >= 71) && ((d & 7) == 7) && ((i & 7) == 0);
}
__device__ __forceinline__ bool masked_ij(int i, int j) {
    return (j >= i) && (j < NPIX) && (i >= 0) && mask_allowed(i, j - i);
}

// closed-form inverse: rank r within row i -> offset d.
__device__ __forceinline__ int rank_to_d(int i, int r) {
    int rem = NPIX - i;
    int c1 = rem < 16 ? rem : 16;
    if (r < c1) return r;
    r -= c1;
    int h2 = (rem - 1) < 31 ? (rem - 1) : 31;
    int c2 = (((i & 1) == 0) && h2 >= 17) ? ((h2 - 17) >> 1) + 1 : 0;
    if (r < c2) return 17 + 2 * r;
    r -= c2;
    int h3 = (rem - 1) < 63 ? (rem - 1) : 63;
    int c3 = (((i & 3) == 0) && h3 >= 35) ? ((h3 - 35) >> 2) + 1 : 0;
    if (r < c3) return 35 + 4 * r;
    r -= c3;
    return 71 + 8 * r;
}

// ==== k_prep: fill(64) | buildB(96 x 8ch) | prepA(576 x 1s) = 736 blocks =======
// R14: fill also compacts active pixels into list[] (count in bar[3], zeroed by
// host-side hipMemsetAsync before launch); prepA split to 1 s-iter per block.
#define PREP_LDS 37888
#define PASTR 148

__global__ __launch_bounds__(256) void k_prep(const float* __restrict__ fea,
                                              const float* __restrict__ w1,
                                              int* __restrict__ qi, int* __restrict__ qj,
                                              int* __restrict__ qidx, int* __restrict__ apix,
                                              double* __restrict__ part, int* __restrict__ bar,
                                              int* __restrict__ list,
                                              unsigned short* __restrict__ Ah,
                                              unsigned short* __restrict__ Al,
                                              unsigned short* __restrict__ Bh,
                                              unsigned short* __restrict__ Bl) {
    extern __shared__ char smp[];
    int tid = threadIdx.x;
    int bid = blockIdx.x;

    if (bid < 64) {
        // ---------------- FILL + compact ----------------
        int* cnt = (int*)smp;
        int* startv = cnt + NPIX;
        if (tid < NPIX) {
            int c = 0;
            for (int d = 0; tid + d < NPIX; ++d) if (mask_allowed(tid, d)) ++c;
            cnt[tid] = c;
        }
        __syncthreads();
        if (tid == 0) {
            int s = 0;
            for (int r = 0; r < NPIX; ++r) { startv[r] = s; s += cnt[r]; }
        }
        __syncthreads();
        int p = bid * 256 + tid;
        int i = p >> 7, j = p & 127;
        int q = -1;
        if (masked_ij(i, j)) {
            int d = j - i, r = 0;
            for (int dd = 0; dd < d; ++dd) r += mask_allowed(i, dd) ? 1 : 0;
            q = startv[i] + r;
            qi[q] = i; qj[q] = j;
        }
        qidx[p] = q;
        int act = 0;
        #pragma unroll
        for (int dy = -1; dy <= 1; ++dy)
            #pragma unroll
            for (int dx = -1; dx <= 1; ++dx)
                if (masked_ij(i + dy, j + dx)) act = 1;
        apix[p] = act;
        if (act) { int idx = atomicAdd(&bar[3], 1); list[idx] = p; }
        if (bid == 0 && tid < 8) part[tid] = 0.0;
    } else if (bid < 160) {
        // ---------------- BUILD B (8 channels / block, 96 blocks) ----------------
        float* tab = (float*)smp;                       // [c 8][lvl 8][x 128] = 32KB
        int* cnt = (int*)(smp + 32768);
        int* startv = (int*)(smp + 33280);              // 129 ints
        int cb = bid - 64, c0 = cb * 8;
        if (tid < NPIX) {
            int c = 0;
            for (int d = 0; tid + d < NPIX; ++d) if (mask_allowed(tid, d)) ++c;
            cnt[tid] = c;
        }
        __syncthreads();
        if (tid == 0) {
            int s = 0;
            for (int r = 0; r < NPIX; ++r) { startv[r] = s; s += cnt[r]; }
            startv[NPIX] = s;
        }
        for (int idx = tid; idx < 8 * NPIX; idx += 256) {
            int c = idx >> 7, x = idx & 127;
            tab[(c * 8) * 128 + x] = fea[(size_t)(c0 + c) * NPIX + x];
        }
        __syncthreads();
        for (int lvl = 1; lvl < 8; ++lvl) {
            int half = 1 << (lvl - 1), full = 1 << lvl;
            for (int idx = tid; idx < 8 * NPIX; idx += 256) {
                int c = idx >> 7, x = idx & 127;
                if (x + full <= NPIX)
                    tab[(c * 8 + lvl) * 128 + x] =
                        fmaxf(tab[(c * 8 + lvl - 1) * 128 + x],
                              tab[(c * 8 + lvl - 1) * 128 + x + half]);
            }
            __syncthreads();
        }
        for (int q = tid; q < NPAD; q += 256) {
            ushort8 vh = {}, vl = {};
            if (q < MASKM) {
                int i = 0;
                #pragma unroll
                for (int s = 64; s >= 1; s >>= 1) {
                    int cand = i + s;
                    if (cand <= 127 && startv[cand] <= q) i = cand;
                }
                int d = rank_to_d(i, q - startv[i]);
                int j = i + d;
                int len = d + 1;
                int lvl = 31 - __clz(len);
                int x2 = j + 1 - (1 << lvl);
                #pragma unroll
                for (int c = 0; c < 8; ++c) {
                    float v = fmaxf(tab[(c * 8 + lvl) * 128 + i], tab[(c * 8 + lvl) * 128 + x2]);
                    unsigned short hh = f2bf(v);
                    vh[c] = hh; vl[c] = f2bf(v - bf2f(hh));
                }
            }
            *(ushort8*)(Bh + (size_t)q * KD + c0) = vh;
            *(ushort8*)(Bl + (size_t)q * KD + c0) = vl;
        }
    } else {
        // ---------------- PREP A (576 blocks, 1 s-iteration each) ----------------
        float* tile = (float*)smp;
        int pb = bid - 160;                             // 0..575
        int co0 = (pb % 12) * 64, ci0 = ((pb / 12) % 12) * 64;
        int s = pb / 144;                               // 0..3
        int cib = ci0 + s * 16;
        for (int idx = tid; idx < 2304; idx += 256) {
            int row = idx / 36, c4 = idx % 36;
            float4 v = *(const float4*)(w1 + (size_t)(co0 + row) * MG + cib * 9 + c4 * 4);
            *(float4*)&tile[row * PASTR + c4 * 4] = v;
        }
        __syncthreads();
        for (int idx = tid; idx < 1152; idx += 256) {
            int tap = idx / 128;
            int rem = idx - tap * 128;
            int co = rem >> 1, half = rem & 1;
            ushort8 vh, vl;
            #pragma unroll
            for (int c = 0; c < 8; ++c) {
                float v = tile[co * PASTR + (half * 8 + c) * 9 + tap];
                unsigned short hi = f2bf(v);
                vh[c] = hi;
                vl[c] = f2bf(v - bf2f(hi));
            }
            size_t ob = (size_t)(tap * 768 + co0 + co) * KD + cib + half * 8;
            *(ushort8*)(Ah + ob) = vh;
            *(ushort8*)(Al + ob) = vl;
        }
    }
}

// ---------------- bf16x3 MFMA GEMM (R12, FROZEN: 86.6us best measured) ----------
#define BUFSZ   73728      // Ah(16K) | Al(16K) | Bh(20K) | Bl(20K)
#define SB_BH   32768

__global__ __launch_bounds__(512, 1) void k_gemm(const unsigned short* __restrict__ Ah,
                                                 const unsigned short* __restrict__ Al,
                                                 const unsigned short* __restrict__ Bh,
                                                 const unsigned short* __restrict__ Bl,
                                                 float* __restrict__ Yt) {
    extern __shared__ char sm[];               // 2 * BUFSZ = 144 KB dynamic LDS
    int tid = threadIdx.x;
    int wave = tid >> 6, lane = tid & 63;

    int bid = (int)blockIdx.x;
    int xcd = bid & 7, loc = bid >> 3;         // 8 XCDs x 27 M-tiles
    int m0 = loc * 256, n0 = xcd * 320;

    int wm = (wave & 3) << 6, wn = (wave >> 2) * 160;
    int r32 = lane & 31, hi2 = lane >> 5;
    int rb  = (r32 >> 4) * 1024 + hi2 * 256 + (r32 & 15) * 16;
    int awb = (wm >> 4) * 1024 + rb;
    int bwb = (wn >> 4) * 1024 + rb;

    int lrow = lane & 15, lchk = lane >> 4;
    const unsigned short* sp[9];
    int so[9];
    #pragma unroll
    for (int s = 0; s < 9; ++s) {
        int gid = wave * 9 + s;
        const unsigned short* base;
        int row0, ldso;
        if (gid < 16)      { base = Ah; row0 = m0 + gid * 16;        ldso = gid * 1024; }
        else if (gid < 32) { base = Al; row0 = m0 + (gid - 16) * 16; ldso = 16384 + (gid - 16) * 1024; }
        else if (gid < 52) { base = Bh; row0 = n0 + (gid - 32) * 16; ldso = SB_BH + (gid - 32) * 1024; }
        else               { base = Bl; row0 = n0 + (gid - 52) * 16; ldso = SB_BH + 20480 + (gid - 52) * 1024; }
        sp[s] = base + (size_t)(row0 + lrow) * KD + lchk * 8;
        so[s] = ldso;
    }

    f32x16 acc[2][5] = {};
    char* CB = sm;
    char* NB = sm + BUFSZ;

    #define STAGE(DST, s, koff) __builtin_amdgcn_global_load_lds( \
        (const __attribute__((address_space(1))) unsigned int*)(sp[s] + (koff)), \
        (__attribute__((address_space(3))) unsigned int*)((DST) + so[s]), 16, 0, 0)
    #define ARD(hl, mf, ks) (*(const bf16x8*)(CB + (hl) * 16384 + awb + (mf) * 2048 + (ks) * 512))
    #define BRD(hl, nf, ks) (*(const bf16x8*)(CB + SB_BH + (hl) * 20480 + bwb + (nf) * 2048 + (ks) * 512))
    #define TRIP(mf, nf, xh, xl, yh, yl) \
        acc[mf][nf] = __builtin_amdgcn_mfma_f32_32x32x16_bf16(xh, yh, acc[mf][nf], 0, 0, 0); \
        acc[mf][nf] = __builtin_amdgcn_mfma_f32_32x32x16_bf16(xh, yl, acc[mf][nf], 0, 0, 0); \
        acc[mf][nf] = __builtin_amdgcn_mfma_f32_32x32x16_bf16(xl, yh, acc[mf][nf], 0, 0, 0);
    #define RBAR __builtin_amdgcn_s_barrier()
    #define SB0  __builtin_amdgcn_sched_barrier(0)
    #define CL6(nf, xh0, xl0, xh1, xl1, yh, yl) \
        __builtin_amdgcn_s_setprio(1); \
        TRIP(0, nf, xh0, xl0, yh, yl) \
        TRIP(1, nf, xh1, xl1, yh, yl) \
        __builtin_amdgcn_s_setprio(0);

    #pragma unroll
    for (int s = 0; s < 9; ++s) STAGE(CB, s, 0);
    __syncthreads();

    for (int t = 0; t < 24; ++t) {
        int kn = (t + 1) * 32;
        bool stg = (t < 23);
        bf16x8 a0h, a0l, a1h, a1l;
        bf16x8 c0h, c0l, c1h, c1l;
        bf16x8 bxh, bxl, byh, byl;

        a0h = ARD(0, 0, 0); a0l = ARD(1, 0, 0);
        a1h = ARD(0, 1, 0); a1l = ARD(1, 1, 0);
        bxh = BRD(0, 0, 0); bxl = BRD(1, 0, 0);
        if (stg) { STAGE(NB, 0, kn); STAGE(NB, 1, kn); STAGE(NB, 2, kn); }
        RBAR;

        byh = BRD(0, 1, 0); byl = BRD(1, 1, 0);
        SB0;
        CL6(0, a0h, a0l, a1h, a1l, bxh, bxl)
        RBAR;
        bxh = BRD(0, 2, 0); bxl = BRD(1, 2, 0);
        SB0;
        CL6(1, a0h, a0l, a1h, a1l, byh, byl)
        RBAR;
        byh = BRD(0, 3, 0); byl = BRD(1, 3, 0);
        if (stg) { STAGE(NB, 3, kn); STAGE(NB, 4, kn); }
        SB0;
        CL6(2, a0h, a0l, a1h, a1l, bxh, bxl)
        RBAR;
        bxh = BRD(0, 4, 0); bxl = BRD(1, 4, 0);
        SB0;
        CL6(3, a0h, a0l, a1h, a1l, byh, byl)
        RBAR;
        c0h = ARD(0, 0, 1); c0l = ARD(1, 0, 1);
        c1h = ARD(0, 1, 1); c1l = ARD(1, 1, 1);
        byh = BRD(0, 0, 1); byl = BRD(1, 0, 1);
        if (stg) { STAGE(NB, 5, kn); STAGE(NB, 6, kn); }
        SB0;
        CL6(4, a0h, a0l, a1h, a1l, bxh, bxl)
        RBAR;
        bxh = BRD(0, 1, 1); bxl = BRD(1, 1, 1);
        SB0;
        CL6(0, c0h, c0l, c1h, c1l, byh, byl)
        RBAR;
        byh = BRD(0, 2, 1); byl = BRD(1, 2, 1);
        if (stg) { STAGE(NB, 7, kn); STAGE(NB, 8, kn); }
        SB0;
        CL6(1, c0h, c0l, c1h, c1l, bxh, bxl)
        RBAR;
        bxh = BRD(0, 3, 1); bxl = BRD(1, 3, 1);
        SB0;
        CL6(2, c0h, c0l, c1h, c1l, byh, byl)
        RBAR;
        byh = BRD(0, 4, 1); byl = BRD(1, 4, 1);
        SB0;
        CL6(3, c0h, c0l, c1h, c1l, bxh, bxl)
        RBAR;
        CL6(4, c0h, c0l, c1h, c1l, byh, byl)

        __syncthreads();
        char* tmp = CB; CB = NB; NB = tmp;
    }

    #pragma unroll
    for (int mf = 0; mf < 2; ++mf)
        #pragma unroll
        for (int nf = 0; nf < 5; ++nf) {
            int n = n0 + wn + nf * 32 + r32;
            size_t rowb = (size_t)n * MG + m0 + wm + mf * 32 + 4 * hi2;
            #pragma unroll
            for (int g = 0; g < 4; ++g) {
                f32x4 v = { acc[mf][nf][g * 4 + 0], acc[mf][nf][g * 4 + 1],
                            acc[mf][nf][g * 4 + 2], acc[mf][nf][g * 4 + 3] };
                *(f32x4*)(Yt + rowb + 8 * g) = v;
            }
        }
    #undef STAGE
    #undef ARD
    #undef BRD
    #undef TRIP
    #undef RBAR
    #undef SB0
    #undef CL6
}

// ---------------- gather: compacted active-pixel list, 1 pixel/wave -------------
// R14: no idle pixel slots (was ~70%), no apix divergence, perfect balance.
// Per-pixel arithmetic identical to R13; grid-stride guards any list size.
__global__ __launch_bounds__(256) void k_gather(const float* __restrict__ Yt,
                                                const int* __restrict__ qidx,
                                                const int* __restrict__ list,
                                                const int* __restrict__ bar,
                                                float* __restrict__ hm,
                                                double* __restrict__ part) {
    __shared__ double red1[256 * 4], red2[256 * 4];
    int tid = threadIdx.x;
    int wave = tid >> 6, lane = tid & 63;
    double a1[3] = {0, 0, 0}, a2[3] = {0, 0, 0};
    int gs[3];
    #pragma unroll
    for (int s = 0; s < 3; ++s) gs[s] = (64 * s + lane) / 48;

    int nact = bar[3];
    for (int wid = blockIdx.x * 4 + wave; wid < nact; wid += gridDim.x * 4) {
        int p = list[wid];
        int y = p >> 7, x = p & 127;
        float4 hv[3] = {};
        #pragma unroll
        for (int tap = 0; tap < 9; ++tap) {
            int i = y + tap / 3 - 1, j = x + tap % 3 - 1;
            if ((unsigned)i < 128u && (unsigned)j < 128u) {
                int q = qidx[i * NPIX + j];
                if (q >= 0) {
                    const float* yr = Yt + (size_t)q * MG + tap * 768 + lane * 4;
                    #pragma unroll
                    for (int s = 0; s < 3; ++s) {
                        float4 v = *(const float4*)(yr + s * 256);
                        hv[s].x += v.x; hv[s].y += v.y; hv[s].z += v.z; hv[s].w += v.w;
                    }
                }
            }
        }
        int qp = qidx[p];
        if (qp >= 0) {
            #pragma unroll
            for (int s = 0; s < 3; ++s)
                *(float4*)(hm + (size_t)qp * KD + s * 256 + lane * 4) = hv[s];
        }
        #pragma unroll
        for (int s = 0; s < 3; ++s) {
            a1[s] += (double)hv[s].x + (double)hv[s].y + (double)hv[s].z + (double)hv[s].w;
            a2[s] += (double)hv[s].x * hv[s].x + (double)hv[s].y * hv[s].y +
                     (double)hv[s].z * hv[s].z + (double)hv[s].w * hv[s].w;
        }
    }
    #pragma unroll
    for (int g = 0; g < 4; ++g) { red1[tid * 4 + g] = 0.0; red2[tid * 4 + g] = 0.0; }
    #pragma unroll
    for (int s = 0; s < 3; ++s) { red1[tid * 4 + gs[s]] = a1[s]; red2[tid * 4 + gs[s]] = a2[s]; }
    __syncthreads();
    if (tid < 8) {
        int g = tid & 3;
        double s = 0.0;
        if (tid < 4) { for (int i = 0; i < 256; ++i) s += red1[i * 4 + g]; }
        else         { for (int i = 0; i < 256; ++i) s += red2[i * 4 + g]; }
        atomicAdd(&part[tid], s);
    }
}

// ================= k_scorenms (R10-proven: relaxed-poll single consumer) =======
#define SNMS_LDS 44544

__global__ __launch_bounds__(256) void k_scorenms(const float* __restrict__ hm,
                                                  const double* __restrict__ part,
                                                  const float* __restrict__ gamma,
                                                  const float* __restrict__ beta,
                                                  const float* __restrict__ w2,
                                                  const float* __restrict__ b2,
                                                  float* __restrict__ scores,
                                                  const int* __restrict__ qi,
                                                  const int* __restrict__ qj,
                                                  const int* __restrict__ durp,
                                                  int* __restrict__ bar,
                                                  float* __restrict__ out) {
    extern __shared__ char smf[];
    int tid = threadIdx.x;
    int bid = (int)blockIdx.x;
    int lane = tid & 63;

    {
        float mu[4], rs[4];
        const double cnt = 192.0 * 16384.0;
        #pragma unroll
        for (int g = 0; g < 4; ++g) {
            double m = part[g] / cnt;
            double v = part[4 + g] / cnt - m * m;
            mu[g] = (float)m;
            rs[g] = (float)(1.0 / sqrt(v + 1e-5));
        }
        int q = bid * 4 + (tid >> 6);
        const float* hp = hm + (size_t)q * KD;
        float s = 0.f;
        for (int c = lane; c < KD; c += 64) {
            int g = c / 192;
            float v = (hp[c] - mu[g]) * rs[g] * gamma[c] + beta[c];
            s += fmaxf(v, 0.f) * w2[c];
        }
        for (int o = 32; o; o >>= 1) s += __shfl_down(s, o, 64);
        if (lane == 0) scores[q] = 1.f / (1.f + expf(-(s + b2[0])));
    }
    __syncthreads();
    if (tid == 0)
        __hip_atomic_fetch_add(&bar[2], 1, __ATOMIC_RELEASE, __HIP_MEMORY_SCOPE_AGENT);
    if (bid != 0) return;

    if (tid == 0) {
        while (__hip_atomic_load(&bar[2], __ATOMIC_RELAXED, __HIP_MEMORY_SCOPE_AGENT) < 637)
            __builtin_amdgcn_s_sleep(8);
        (void)__hip_atomic_load(&bar[2], __ATOMIC_ACQUIRE, __HIP_MEMORY_SCOPE_AGENT);
    }
    __syncthreads();

    {
        unsigned long long* key = (unsigned long long*)smf;
        float* ss = (float*)(smf + 20384);
        float* ee = (float*)(smf + 30576);
        unsigned char* st = (unsigned char*)(smf + 40768);
        unsigned long long* wm0 = (unsigned long long*)(smf + 43328);
        unsigned long long* wm1 = (unsigned long long*)(smf + 43360);
        __shared__ int sh_keeper, keepq[5];
        __shared__ float sh_s0, sh_e0;

        float delta = (float)(*durp) / 128.f;
        for (int i = tid; i < MASKM; i += 256) {
            unsigned sb = __float_as_uint(scores[i]);
            key[i] = ((unsigned long long)sb << 32) | (unsigned)(4095 - i);
            ss[i] = qi[i] * delta;
            ee[i] = (qj[i] + 1) * delta;
            st[i] = 0;
        }
        __syncthreads();
        for (int round = 0; round < 5; ++round) {
            unsigned long long b0 = 0, b1 = 0;
            for (int i = tid; i < MASKM; i += 256) {
                unsigned char s = st[i];
                unsigned long long k = key[i];
                if (s == 0) { if (k > b0) b0 = k; }
                else if (s == 1) { if (k > b1) b1 = k; }
            }
            for (int o = 32; o; o >>= 1) {
                unsigned lo0 = __shfl_down((unsigned)b0, o, 64);
                unsigned hi0 = __shfl_down((unsigned)(b0 >> 32), o, 64);
                unsigned long long u0 = ((unsigned long long)hi0 << 32) | lo0;
                unsigned lo1 = __shfl_down((unsigned)b1, o, 64);
                unsigned hi1 = __shfl_down((unsigned)(b1 >> 32), o, 64);
                unsigned long long u1 = ((unsigned long long)hi1 << 32) | lo1;
                if (u0 > b0) b0 = u0;
                if (u1 > b1) b1 = u1;
            }
            if ((tid & 63) == 0) { wm0[tid >> 6] = b0; wm1[tid >> 6] = b1; }
            __syncthreads();
            if (tid == 0) {
                unsigned long long B0 = 0, B1 = 0;
                for (int w = 0; w < 4; ++w) {
                    if (wm0[w] > B0) B0 = wm0[w];
                    if (wm1[w] > B1) B1 = wm1[w];
                }
                int keeper = (B0 != 0);
                unsigned long long B = keeper ? B0 : B1;
                int q = 4095 - (int)(B & 0xFFFFFFFFull);
                st[q] = keeper ? 2 : 3;
                sh_keeper = keeper;
                sh_s0 = ss[q]; sh_e0 = ee[q];
                keepq[round] = q;
            }
            __syncthreads();
            if (sh_keeper) {
                float s0 = sh_s0, e0 = sh_e0;
                for (int i = tid; i < MASKM; i += 256) {
                    if (st[i] == 0) {
                        float inter = fminf(ee[i], e0) - fmaxf(ss[i], s0);
                        if (inter > 0.f) {
                            float uni = fmaxf(ee[i], e0) - fminf(ss[i], s0);
                            if (inter / uni > 0.5f) st[i] = 1;
                        }
                    }
                }
            }
            __syncthreads();
        }
        if (tid < 5) { out[tid * 2] = ss[keepq[tid]]; out[tid * 2 + 1] = ee[keepq[tid]]; }
    }
}

// ---------------- launch ----------------
extern "C" void kernel_launch(void* const* d_in, const int* in_sizes, int n_in,
                              void* d_out, int out_size, void* d_ws, size_t ws_size,
                              hipStream_t stream) {
    const float* fea   = (const float*)d_in[0];
    const int*   dur   = (const int*)d_in[1];
    const float* w1    = (const float*)d_in[2];
    const float* gamma = (const float*)d_in[3];
    const float* beta  = (const float*)d_in[4];
    const float* w2    = (const float*)d_in[5];
    const float* b2    = (const float*)d_in[6];
    float* out = (float*)d_out;

    char* ws = (char*)d_ws;
    int*    qi     = (int*)(ws + OFF_QI);
    int*    qj     = (int*)(ws + OFF_QJ);
    int*    qidx   = (int*)(ws + OFF_QIDX);
    int*    apix   = (int*)(ws + OFF_APIX);
    int*    bar    = (int*)(ws + OFF_BAR);
    int*    list   = (int*)(ws + OFF_LIST);
    double* part   = (double*)(ws + OFF_PART);
    float*  scores = (float*)(ws + OFF_SC);
    float*  hm     = (float*)(ws + OFF_HM);
    unsigned short* AhU = (unsigned short*)(ws + OFF_AH);
    unsigned short* AlU = (unsigned short*)(ws + OFF_AL);
    unsigned short* BhU = (unsigned short*)(ws + OFF_BH);
    unsigned short* BlU = (unsigned short*)(ws + OFF_BL);
    float*  Yt     = (float*)(ws + OFF_YT);

    static bool attr_set = false;
    if (!attr_set) {
        hipFuncSetAttribute((const void*)k_prep,
                            hipFuncAttributeMaxDynamicSharedMemorySize, PREP_LDS);
        hipFuncSetAttribute((const void*)k_gemm,
                            hipFuncAttributeMaxDynamicSharedMemorySize, 2 * BUFSZ);
        hipFuncSetAttribute((const void*)k_scorenms,
                            hipFuncAttributeMaxDynamicSharedMemorySize, SNMS_LDS);
        attr_set = true;
    }

    hipMemsetAsync(bar, 0, 16, stream);   // zero sync counters + list count
    k_prep<<<736, 256, PREP_LDS, stream>>>(fea, w1, qi, qj, qidx, apix, part, bar,
                                           list, AhU, AlU, BhU, BlU);
    k_gemm<<<216, 512, 2 * BUFSZ, stream>>>(AhU, AlU, BhU, BlU, Yt);
    k_gather<<<1536, 256, 0, stream>>>(Yt, qidx, list, bar, hm, part);
    k_scorenms<<<637, 256, SNMS_LDS, stream>>>(hm, part, gamma, beta, w2, b2,
                                               scores, qi, qj, dur, bar, out);
}